// Round 4
// baseline (2676.160 us; speedup 1.0000x reference)
//
#include <hip/hip_runtime.h>
#include <math.h>

#define NS 4
#define NB 32
#define CIN 128
#define NCOUT 256
#define HWN 256
#define ND 1152
#define NK 8192   // NB*HWN
static const size_t D2 = (size_t)ND * ND;

typedef __attribute__((ext_vector_type(8))) short bf16x8;
typedef __attribute__((ext_vector_type(4))) float f32x4;

static __device__ inline unsigned short f2bf(float x) {
  unsigned int u = __float_as_uint(x);
  unsigned int r = (u + 0x7fffu + ((u >> 16) & 1u)) >> 16;
  return (unsigned short)r;
}
static __device__ inline float bf2f(unsigned short h) {
  return __uint_as_float(((unsigned int)h) << 16);
}

// ---------------- small prep kernels ----------------

__global__ void k_sqrtp(const float* __restrict__ lp, float* __restrict__ sp,
                        float* __restrict__ pp) {
  int b = threadIdx.x;
  if (b < NB) sp[b] = expf(0.5f * lp[b]);
  if (b < 8) pp[b] = 0.f;
}

__global__ __launch_bounds__(256) void k_patches(const float* __restrict__ X,
                                                 const float* __restrict__ sp,
                                                 unsigned short* __restrict__ Phi,
                                                 unsigned short* __restrict__ Plo) {
  int d = blockIdx.x, s = blockIdx.y, p = threadIdx.x;
  int c = d / 9, r = d % 9, ky = r / 3, kx = r % 3;
  int yy = (p >> 4) + ky - 1, xx = (p & 15) + kx - 1;
  bool ok = (yy >= 0 && yy < 16 && xx >= 0 && xx < 16);
  int xoff = yy * 16 + xx;
  size_t base = ((size_t)s * ND + d) * NK + p;
  for (int b = 0; b < NB; ++b) {
    float v = 0.f;
    if (ok) v = X[((size_t)(s * NB + b) * CIN + c) * HWN + xoff] * sp[b];
    unsigned short h = f2bf(v);
    Phi[base + b * HWN] = h;
    Plo[base + b * HWN] = f2bf(v - bf2f(h));
  }
}

__global__ __launch_bounds__(256) void k_ytt(const float* __restrict__ u,
                                             const float* __restrict__ sp,
                                             unsigned short* __restrict__ Yhi,
                                             unsigned short* __restrict__ Ylo) {
  int c = blockIdx.x, p = threadIdx.x;
  for (int b = 0; b < NB; ++b) {
    float v = sp[b] * u[((size_t)b * NCOUT + c) * HWN + p];
    unsigned short h = f2bf(v);
    size_t idx = (size_t)c * NK + b * HWN + p;
    Yhi[idx] = h;
    Ylo[idx] = f2bf(v - bf2f(h));
  }
}

// ---------------- bf16x3 MFMA fused XLX (lower 128-tiles) + XLY ----------------
__global__ __launch_bounds__(256) void k_gemm_mfma(
    const unsigned short* __restrict__ Phi, const unsigned short* __restrict__ Plo,
    const unsigned short* __restrict__ Yhi, const unsigned short* __restrict__ Ylo,
    float* __restrict__ prec, float* __restrict__ XLY) {
  int jt = blockIdx.x, it = blockIdx.y, s = blockIdx.z;
  bool isX = (jt <= it);
  if (!isX && jt < 9) return;
  int i0 = it * 128;
  int j0;
  const unsigned short *Bh, *Bl;
  if (isX) {
    j0 = jt * 128;
    Bh = Phi + ((size_t)s * ND + j0) * NK;
    Bl = Plo + ((size_t)s * ND + j0) * NK;
  } else {
    j0 = (jt - 9) * 128;
    Bh = Yhi + (size_t)j0 * NK;
    Bl = Ylo + (size_t)j0 * NK;
  }
  const unsigned short* Ah = Phi + ((size_t)s * ND + i0) * NK;
  const unsigned short* Al = Plo + ((size_t)s * ND + i0) * NK;

  __shared__ unsigned short sAh[4096], sAl[4096], sBh[4096], sBl[4096];
  int tid = threadIdx.x, wave = tid >> 6, lane = tid & 63;
  int wr = wave >> 1, wc = wave & 1;

  f32x4 zero = {0.f, 0.f, 0.f, 0.f};
  f32x4 acc[4][4];
#pragma unroll
  for (int m = 0; m < 4; ++m)
#pragma unroll
    for (int n = 0; n < 4; ++n) acc[m][n] = zero;

  const unsigned short* srcs[4] = {Ah, Al, Bh, Bl};
  unsigned short* dsts[4] = {sAh, sAl, sBh, sBl};
  int r0l = lane >> 2;
  int ke = (lane & 3) * 8;
  int arow0 = wr * 64 + (lane & 15);
  int brow0 = wc * 64 + (lane & 15);
  int koff = (lane >> 4) * 8;

  for (int k0 = 0; k0 < NK; k0 += 32) {
    __syncthreads();
#pragma unroll
    for (int f = 0; f < 4; ++f) {
#pragma unroll
      for (int cc = 0; cc < 2; ++cc) {
        int c = wave * 2 + cc;
        const unsigned short* g = srcs[f] + (size_t)(c * 16 + r0l) * NK + k0 + ke;
        unsigned short* l = dsts[f] + c * 512;
        __builtin_amdgcn_global_load_lds(
            (const __attribute__((address_space(1))) void*)g,
            (__attribute__((address_space(3))) void*)l, 16, 0, 0);
      }
    }
    __syncthreads();
    bf16x8 ah[4], al[4], bh[4], bl[4];
#pragma unroll
    for (int m = 0; m < 4; ++m) {
      int off = (arow0 + m * 16) * 32 + koff;
      ah[m] = *(const bf16x8*)&sAh[off];
      al[m] = *(const bf16x8*)&sAl[off];
    }
#pragma unroll
    for (int n = 0; n < 4; ++n) {
      int off = (brow0 + n * 16) * 32 + koff;
      bh[n] = *(const bf16x8*)&sBh[off];
      bl[n] = *(const bf16x8*)&sBl[off];
    }
#pragma unroll
    for (int m = 0; m < 4; ++m)
#pragma unroll
      for (int n = 0; n < 4; ++n) {
        acc[m][n] = __builtin_amdgcn_mfma_f32_16x16x32_bf16(ah[m], bh[n], acc[m][n], 0, 0, 0);
        acc[m][n] = __builtin_amdgcn_mfma_f32_16x16x32_bf16(ah[m], bl[n], acc[m][n], 0, 0, 0);
        acc[m][n] = __builtin_amdgcn_mfma_f32_16x16x32_bf16(al[m], bh[n], acc[m][n], 0, 0, 0);
      }
  }

  if (isX) {
    float* base = prec + (size_t)s * D2;
#pragma unroll
    for (int m = 0; m < 4; ++m) {
      int row = i0 + wr * 64 + m * 16 + (lane >> 4) * 4;
#pragma unroll
      for (int n = 0; n < 4; ++n) {
        int col = j0 + wc * 64 + n * 16 + (lane & 15);
        float* cp = base + (size_t)row * ND + col;
#pragma unroll
        for (int r = 0; r < 4; ++r) {
          float v = acc[m][n][r];
          if (row + r == col) v += 1.f;
          cp[(size_t)r * ND] = v;
        }
      }
    }
  } else {
    float* base = XLY + (size_t)s * ND * NCOUT;
#pragma unroll
    for (int m = 0; m < 4; ++m) {
      int row = i0 + wr * 64 + m * 16 + (lane >> 4) * 4;
#pragma unroll
      for (int n = 0; n < 4; ++n) {
        int col = j0 + wc * 64 + n * 16 + (lane & 15);
        float* cp = base + (size_t)row * NCOUT + col;
#pragma unroll
        for (int r = 0; r < 4; ++r) cp[(size_t)r * NCOUT] = acc[m][n][r];
      }
    }
  }
}

// ---------------- blocked Cholesky, NB=64 (unchanged) ----------------
__global__ __launch_bounds__(64) void k_chol_panel(float* __restrict__ L,
                                                   float* __restrict__ invd,
                                                   float* __restrict__ logd, int q) {
  const int s = blockIdx.x;
  const int strip = blockIdx.y;
  const int lane = threadIdx.x;
  const int j0 = q * 64;
  float* Ls = L + (size_t)s * D2;
  __shared__ float tile[64][65];
  for (int r = 0; r < 64; ++r) tile[r][lane] = Ls[(size_t)(j0 + r) * ND + j0 + lane];
  __syncthreads();
  float a[64];
#pragma unroll
  for (int t = 0; t < 64; ++t) a[t] = tile[lane][t];
  float diagv = 1.f;
#pragma unroll
  for (int j = 0; j < 64; ++j) {
    float dj = __shfl(a[j], j, 64);
    float rinv = 1.0f / sqrtf(dj);
    a[j] *= rinv;
    if (lane == j) diagv = a[j];
#pragma unroll
    for (int t = j + 1; t < 64; ++t) {
      float ltj = __shfl(a[j], t, 64);
      a[t] = fmaf(-a[j], ltj, a[t]);
    }
  }
  if (strip == 0) {
    __syncthreads();
#pragma unroll
    for (int t = 0; t < 64; ++t) tile[lane][t] = a[t];
    __syncthreads();
    for (int r = 0; r < 64; ++r) Ls[(size_t)(j0 + r) * ND + j0 + lane] = tile[r][lane];
    invd[s * ND + j0 + lane] = 1.0f / diagv;
    logd[s * ND + j0 + lane] = logf(diagv);
  } else {
    const int r0 = j0 + 64 * strip;
    __syncthreads();
    for (int r = 0; r < 64; ++r) tile[r][lane] = Ls[(size_t)(r0 + r) * ND + j0 + lane];
    __syncthreads();
    float b[64];
#pragma unroll
    for (int t = 0; t < 64; ++t) b[t] = tile[lane][t];
#pragma unroll
    for (int j = 0; j < 64; ++j) {
      float dj = __shfl(a[j], j, 64);
      b[j] *= (1.0f / dj);
#pragma unroll
      for (int t = j + 1; t < 64; ++t) {
        float ltj = __shfl(a[j], t, 64);
        b[t] = fmaf(-b[j], ltj, b[t]);
      }
    }
    __syncthreads();
#pragma unroll
    for (int t = 0; t < 64; ++t) tile[lane][t] = b[t];
    __syncthreads();
    for (int r = 0; r < 64; ++r) Ls[(size_t)(r0 + r) * ND + j0 + lane] = tile[r][lane];
  }
}

__global__ __launch_bounds__(256) void k_chol_update(float* __restrict__ L, int q) {
  int ti = blockIdx.x, tj = blockIdx.y, s = blockIdx.z;
  if (ti < tj) return;
  int j0 = q * 64;
  int r0 = j0 + 64 + ti * 64;
  int c0 = j0 + 64 + tj * 64;
  float* Ls = L + (size_t)s * D2;
  __shared__ float At[64][64];
  __shared__ float Bt[64][64];
  int tid = threadIdx.x;
  {
    int a = tid >> 2, km = (tid & 3) * 4;
#pragma unroll
    for (int m = 0; m < 4; ++m) {
      float4 v = *(const float4*)(Ls + (size_t)(r0 + a) * ND + j0 + km + m * 16);
      At[km + m * 16 + 0][a] = v.x;
      At[km + m * 16 + 1][a] = v.y;
      At[km + m * 16 + 2][a] = v.z;
      At[km + m * 16 + 3][a] = v.w;
      float4 w = *(const float4*)(Ls + (size_t)(c0 + a) * ND + j0 + km + m * 16);
      Bt[km + m * 16 + 0][a] = w.x;
      Bt[km + m * 16 + 1][a] = w.y;
      Bt[km + m * 16 + 2][a] = w.z;
      Bt[km + m * 16 + 3][a] = w.w;
    }
  }
  __syncthreads();
  int tx = tid & 15, ty = tid >> 4;
  float acc[4][4] = {};
#pragma unroll
  for (int k = 0; k < 64; ++k) {
    float4 a4 = *(const float4*)&At[k][ty * 4];
    float4 b4 = *(const float4*)&Bt[k][tx * 4];
    float ar[4] = {a4.x, a4.y, a4.z, a4.w};
    float br[4] = {b4.x, b4.y, b4.z, b4.w};
#pragma unroll
    for (int r = 0; r < 4; ++r)
#pragma unroll
      for (int e = 0; e < 4; ++e) acc[r][e] = fmaf(ar[r], br[e], acc[r][e]);
  }
#pragma unroll
  for (int r = 0; r < 4; ++r) {
    float* cp = Ls + (size_t)(r0 + ty * 4 + r) * ND + c0 + tx * 4;
    float4 c = *(const float4*)cp;
    c.x -= acc[r][0]; c.y -= acc[r][1]; c.z -= acc[r][2]; c.w -= acc[r][3];
    *(float4*)cp = c;
  }
}

// ---------------- invert 128x128 diag blocks: iD = inv(L_qq) ----------------
// [A 0; B C]^-1 = [iA 0; -iC*B*iA, iC]
__global__ __launch_bounds__(64) void k_invd128(const float* __restrict__ L,
                                                float* __restrict__ iD) {
  int q = blockIdx.x, s = blockIdx.y, lane = threadIdx.x;
  const float* Ls = L + (size_t)s * D2;
  float* out = iD + ((size_t)(s * 9 + q)) * 16384;
  int b0 = q * 128;
  __shared__ float Ds[64][65];
  __shared__ float Xls[64][64];
  __shared__ float T[64][64];
  for (int rr = 0; rr < 64; ++rr) Ds[rr][lane] = Ls[(size_t)(b0 + rr) * ND + b0 + lane];
  __syncthreads();
  for (int t = 0; t < 64; ++t) {
    float sum = (t == lane) ? 1.f : 0.f;
    for (int k = lane; k < t; ++k) sum = fmaf(-Ds[t][k], Xls[k][lane], sum);
    Xls[t][lane] = (lane <= t) ? sum / Ds[t][t] : 0.f;
  }
  __syncthreads();
  for (int t = 0; t < 64; ++t) {
    out[t * 128 + lane] = Xls[t][lane];
    out[t * 128 + 64 + lane] = 0.f;
  }
  // T = L21 @ iA
  for (int rr = 0; rr < 64; ++rr) Ds[rr][lane] = Ls[(size_t)(b0 + 64 + rr) * ND + b0 + lane];
  __syncthreads();
  for (int rr = 0; rr < 64; ++rr) {
    float sum = 0.f;
    for (int k = lane; k < 64; ++k) sum = fmaf(Ds[rr][k], Xls[k][lane], sum);
    T[rr][lane] = sum;
  }
  __syncthreads();
  // iC
  for (int rr = 0; rr < 64; ++rr) Ds[rr][lane] = Ls[(size_t)(b0 + 64 + rr) * ND + b0 + 64 + lane];
  __syncthreads();
  for (int t = 0; t < 64; ++t) {
    float sum = (t == lane) ? 1.f : 0.f;
    for (int k = lane; k < t; ++k) sum = fmaf(-Ds[t][k], Xls[k][lane], sum);
    Xls[t][lane] = (lane <= t) ? sum / Ds[t][t] : 0.f;
  }
  __syncthreads();
  for (int t = 0; t < 64; ++t) out[(64 + t) * 128 + 64 + lane] = Xls[t][lane];
  __syncthreads();
  // G = -iC @ T
  for (int rr = 0; rr < 64; ++rr) {
    float sum = 0.f;
    for (int k = 0; k <= rr; ++k) sum = fmaf(Xls[rr][k], T[k][lane], sum);
    out[(64 + rr) * 128 + lane] = -sum;
  }
}

// ---------------- persistent flag-synced forward solve ----------------
// grid (9, 4, NS): r=row-block(128), ct=col-tile(64), s. All 144 blocks co-resident.
__global__ __launch_bounds__(256) void k_fsolve(const float* __restrict__ L,
                                                const float* __restrict__ iD,
                                                const float* __restrict__ Bsrc,
                                                float* __restrict__ Xf,
                                                int* __restrict__ flags) {
  int r = blockIdx.x, ct = blockIdx.y, s = blockIdx.z;
  int rb = r * 128, cb = ct * 64;
  const float* Ls = L + (size_t)s * D2;
  const float* Dq = iD + ((size_t)(s * 9 + r)) * 16384;
  const float* Bs = Bsrc + (size_t)s * ND * NCOUT;
  float* Xs = Xf + (size_t)s * ND * NCOUT;
  int fbase = (s * 4 + ct) * 9;

  __shared__ float sA[32][132];
  __shared__ float sB[32][68];
  int tid = threadIdx.x, tx = tid & 15, ty = tid >> 4;
  float acc[8][4];
#pragma unroll
  for (int ii = 0; ii < 8; ++ii) {
    float4 v = *(const float4*)(Bs + (size_t)(rb + ty * 8 + ii) * NCOUT + cb + tx * 4);
    acc[ii][0] = v.x; acc[ii][1] = v.y; acc[ii][2] = v.z; acc[ii][3] = v.w;
  }
  for (int q = 0; q < r; ++q) {
    if (tid == 0) {
      while (__hip_atomic_load(&flags[fbase + q], __ATOMIC_ACQUIRE,
                               __HIP_MEMORY_SCOPE_AGENT) == 0)
        __builtin_amdgcn_s_sleep(2);
    }
    __syncthreads();
    int qb = q * 128;
    for (int kk = 0; kk < 4; ++kk) {
      __syncthreads();
      {  // sA[k][i] = L[rb+i][qb+kk*32+k]
        int i = tid >> 1, kb = (tid & 1) * 16;
        const float* src = Ls + (size_t)(rb + i) * ND + qb + kk * 32 + kb;
#pragma unroll
        for (int m = 0; m < 4; ++m) {
          float4 v = *(const float4*)(src + m * 4);
          sA[kb + m * 4 + 0][i] = v.x;
          sA[kb + m * 4 + 1][i] = v.y;
          sA[kb + m * 4 + 2][i] = v.z;
          sA[kb + m * 4 + 3][i] = v.w;
        }
      }
      {  // sB[k][j] = Xq[qb+kk*32+k][cb+j] (agent loads)
        int k = tid >> 3, jb = (tid & 7) * 8;
        const float* src = Xs + (size_t)(qb + kk * 32 + k) * NCOUT + cb + jb;
#pragma unroll
        for (int e = 0; e < 8; ++e)
          sB[k][jb + e] = __hip_atomic_load(src + e, __ATOMIC_RELAXED,
                                            __HIP_MEMORY_SCOPE_AGENT);
      }
      __syncthreads();
#pragma unroll
      for (int k = 0; k < 32; ++k) {
        float4 a0 = *(const float4*)&sA[k][ty * 8];
        float4 a1 = *(const float4*)&sA[k][ty * 8 + 4];
        float4 b0 = *(const float4*)&sB[k][tx * 4];
        float a[8] = {a0.x, a0.y, a0.z, a0.w, a1.x, a1.y, a1.z, a1.w};
        float b[4] = {b0.x, b0.y, b0.z, b0.w};
#pragma unroll
        for (int ii = 0; ii < 8; ++ii)
#pragma unroll
          for (int j = 0; j < 4; ++j) acc[ii][j] = fmaf(-a[ii], b[j], acc[ii][j]);
      }
    }
  }
  // diag: acc2 = iD[r] @ acc
  float acc2[8][4] = {};
  for (int kk = 0; kk < 4; ++kk) {
    __syncthreads();
    if ((ty >> 2) == kk) {
      int kloc = ty * 8 - kk * 32;
#pragma unroll
      for (int ii = 0; ii < 8; ++ii) {
        float4 v = {acc[ii][0], acc[ii][1], acc[ii][2], acc[ii][3]};
        *(float4*)&sB[kloc + ii][tx * 4] = v;
      }
    }
    {  // sA[k][i] = iD[i][kk*32+k]
      int i = tid >> 1, kb = (tid & 1) * 16;
      const float* src = Dq + (size_t)i * 128 + kk * 32 + kb;
#pragma unroll
      for (int m = 0; m < 4; ++m) {
        float4 v = *(const float4*)(src + m * 4);
        sA[kb + m * 4 + 0][i] = v.x;
        sA[kb + m * 4 + 1][i] = v.y;
        sA[kb + m * 4 + 2][i] = v.z;
        sA[kb + m * 4 + 3][i] = v.w;
      }
    }
    __syncthreads();
#pragma unroll
    for (int k = 0; k < 32; ++k) {
      float4 a0 = *(const float4*)&sA[k][ty * 8];
      float4 a1 = *(const float4*)&sA[k][ty * 8 + 4];
      float4 b0 = *(const float4*)&sB[k][tx * 4];
      float a[8] = {a0.x, a0.y, a0.z, a0.w, a1.x, a1.y, a1.z, a1.w};
      float b[4] = {b0.x, b0.y, b0.z, b0.w};
#pragma unroll
      for (int ii = 0; ii < 8; ++ii)
#pragma unroll
        for (int j = 0; j < 4; ++j) acc2[ii][j] = fmaf(a[ii], b[j], acc2[ii][j]);
    }
  }
  // publish
#pragma unroll
  for (int ii = 0; ii < 8; ++ii) {
    float* dst = Xs + (size_t)(rb + ty * 8 + ii) * NCOUT + cb + tx * 4;
#pragma unroll
    for (int j = 0; j < 4; ++j)
      __hip_atomic_store(dst + j, acc2[ii][j], __ATOMIC_RELAXED,
                         __HIP_MEMORY_SCOPE_AGENT);
  }
  __syncthreads();
  if (tid == 0)
    __hip_atomic_store(&flags[fbase + r], 1, __ATOMIC_RELEASE,
                       __HIP_MEMORY_SCOPE_AGENT);
}

// ---------------- persistent flag-synced backward solve (fused addz + writewm) ----------------
__global__ __launch_bounds__(256) void k_bsolve(const float* __restrict__ L,
                                                const float* __restrict__ iD,
                                                const float* __restrict__ Xf,
                                                const float* __restrict__ Z,
                                                float* __restrict__ Xb,
                                                float* __restrict__ Wm,
                                                float* __restrict__ pp,
                                                int* __restrict__ flags) {
  int r = 8 - blockIdx.x, ct = blockIdx.y, s = blockIdx.z;
  int rb = r * 128, cb = ct * 64;
  const float* Ls = L + (size_t)s * D2;
  const float* Dq = iD + ((size_t)(s * 9 + r)) * 16384;
  const float* Xfs = Xf + (size_t)s * ND * NCOUT;
  float* Xs = Xb + (size_t)s * ND * NCOUT;
  int fbase = 144 + (s * 4 + ct) * 9;

  __shared__ float sA[32][132];
  __shared__ float sB[32][68];
  __shared__ float red[8];
  int tid = threadIdx.x, tx = tid & 15, ty = tid >> 4;
  int wave = tid >> 6, lane = tid & 63;

  float acc[8][4];
#pragma unroll
  for (int ii = 0; ii < 8; ++ii) {
    float4 v = *(const float4*)(Xfs + (size_t)(rb + ty * 8 + ii) * NCOUT + cb + tx * 4);
    acc[ii][0] = v.x; acc[ii][1] = v.y; acc[ii][2] = v.z; acc[ii][3] = v.w;
  }
  // add Z^T tile + zsum (Z[s][c][d]); stage transposed via sA in 32-d chunks
  float zp = 0.f;
  for (int kk = 0; kk < 4; ++kk) {
    __syncthreads();
    {
      int c = tid >> 2, d8 = (tid & 3) * 8;
      const float* src = Z + ((size_t)(s * NCOUT) + cb + c) * ND + rb + kk * 32 + d8;
      float4 v0 = *(const float4*)src;
      float4 v1 = *(const float4*)(src + 4);
      sA[d8 + 0][c] = v0.x; sA[d8 + 1][c] = v0.y; sA[d8 + 2][c] = v0.z; sA[d8 + 3][c] = v0.w;
      sA[d8 + 4][c] = v1.x; sA[d8 + 5][c] = v1.y; sA[d8 + 6][c] = v1.z; sA[d8 + 7][c] = v1.w;
      zp += v0.x * v0.x + v0.y * v0.y + v0.z * v0.z + v0.w * v0.w;
      zp += v1.x * v1.x + v1.y * v1.y + v1.z * v1.z + v1.w * v1.w;
    }
    __syncthreads();
    if ((ty >> 2) == kk) {
      int kloc = ty * 8 - kk * 32;
#pragma unroll
      for (int ii = 0; ii < 8; ++ii) {
        float4 v = *(const float4*)&sA[kloc + ii][tx * 4];
        acc[ii][0] += v.x; acc[ii][1] += v.y; acc[ii][2] += v.z; acc[ii][3] += v.w;
      }
    }
  }
#pragma unroll
  for (int m2 = 32; m2 >= 1; m2 >>= 1) zp += __shfl_xor(zp, m2, 64);
  if (lane == 0) red[wave] = zp;
  __syncthreads();
  if (tid == 0) atomicAdd(pp + s, red[0] + red[1] + red[2] + red[3]);

  for (int q = 8; q > r; --q) {
    if (tid == 0) {
      while (__hip_atomic_load(&flags[fbase + q], __ATOMIC_ACQUIRE,
                               __HIP_MEMORY_SCOPE_AGENT) == 0)
        __builtin_amdgcn_s_sleep(2);
    }
    __syncthreads();
    int qb = q * 128;
    for (int kk = 0; kk < 4; ++kk) {
      __syncthreads();
      {  // sA[k][i] = L[qb+kk*32+k][rb+i]  (natural row copy)
        int k = tid >> 3, ib = (tid & 7) * 16;
        const float* src = Ls + (size_t)(qb + kk * 32 + k) * ND + rb + ib;
#pragma unroll
        for (int m = 0; m < 4; ++m)
          *(float4*)&sA[k][ib + m * 4] = *(const float4*)(src + m * 4);
      }
      {
        int k = tid >> 3, jb = (tid & 7) * 8;
        const float* src = Xs + (size_t)(qb + kk * 32 + k) * NCOUT + cb + jb;
#pragma unroll
        for (int e = 0; e < 8; ++e)
          sB[k][jb + e] = __hip_atomic_load(src + e, __ATOMIC_RELAXED,
                                            __HIP_MEMORY_SCOPE_AGENT);
      }
      __syncthreads();
#pragma unroll
      for (int k = 0; k < 32; ++k) {
        float4 a0 = *(const float4*)&sA[k][ty * 8];
        float4 a1 = *(const float4*)&sA[k][ty * 8 + 4];
        float4 b0 = *(const float4*)&sB[k][tx * 4];
        float a[8] = {a0.x, a0.y, a0.z, a0.w, a1.x, a1.y, a1.z, a1.w};
        float b[4] = {b0.x, b0.y, b0.z, b0.w};
#pragma unroll
        for (int ii = 0; ii < 8; ++ii)
#pragma unroll
          for (int j = 0; j < 4; ++j) acc[ii][j] = fmaf(-a[ii], b[j], acc[ii][j]);
      }
    }
  }
  // diag: acc2 = iD[r]^T @ acc  -> sA[k][i] = iD[k][i] (natural row copy)
  float acc2[8][4] = {};
  for (int kk = 0; kk < 4; ++kk) {
    __syncthreads();
    if ((ty >> 2) == kk) {
      int kloc = ty * 8 - kk * 32;
#pragma unroll
      for (int ii = 0; ii < 8; ++ii) {
        float4 v = {acc[ii][0], acc[ii][1], acc[ii][2], acc[ii][3]};
        *(float4*)&sB[kloc + ii][tx * 4] = v;
      }
    }
    {
      int k = tid >> 3, ib = (tid & 7) * 16;
      const float* src = Dq + (size_t)(kk * 32 + k) * 128 + ib;
#pragma unroll
      for (int m = 0; m < 4; ++m)
        *(float4*)&sA[k][ib + m * 4] = *(const float4*)(src + m * 4);
    }
    __syncthreads();
#pragma unroll
    for (int k = 0; k < 32; ++k) {
      float4 a0 = *(const float4*)&sA[k][ty * 8];
      float4 a1 = *(const float4*)&sA[k][ty * 8 + 4];
      float4 b0 = *(const float4*)&sB[k][tx * 4];
      float a[8] = {a0.x, a0.y, a0.z, a0.w, a1.x, a1.y, a1.z, a1.w};
      float b[4] = {b0.x, b0.y, b0.z, b0.w};
#pragma unroll
      for (int ii = 0; ii < 8; ++ii)
#pragma unroll
        for (int j = 0; j < 4; ++j) acc2[ii][j] = fmaf(a[ii], b[j], acc2[ii][j]);
    }
  }
  // publish X for consumers first
#pragma unroll
  for (int ii = 0; ii < 8; ++ii) {
    float* dst = Xs + (size_t)(rb + ty * 8 + ii) * NCOUT + cb + tx * 4;
#pragma unroll
    for (int j = 0; j < 4; ++j)
      __hip_atomic_store(dst + j, acc2[ii][j], __ATOMIC_RELAXED,
                         __HIP_MEMORY_SCOPE_AGENT);
  }
  __syncthreads();
  if (tid == 0)
    __hip_atomic_store(&flags[fbase + r], 1, __ATOMIC_RELEASE,
                       __HIP_MEMORY_SCOPE_AGENT);
  // wsum
  float wp = 0.f;
#pragma unroll
  for (int ii = 0; ii < 8; ++ii)
#pragma unroll
    for (int j = 0; j < 4; ++j) wp += acc2[ii][j] * acc2[ii][j];
#pragma unroll
  for (int m2 = 32; m2 >= 1; m2 >>= 1) wp += __shfl_xor(wp, m2, 64);
  __syncthreads();
  if (lane == 0) red[wave] = wp;
  __syncthreads();
  if (tid == 0) atomicAdd(pp + 4 + s, red[0] + red[1] + red[2] + red[3]);
  // Wm[s][c][d] = acc2[d][c]: transpose via sB in 32-d chunks
  for (int kk = 0; kk < 4; ++kk) {
    __syncthreads();
    if ((ty >> 2) == kk) {
      int kloc = ty * 8 - kk * 32;
#pragma unroll
      for (int ii = 0; ii < 8; ++ii) {
        float4 v = {acc2[ii][0], acc2[ii][1], acc2[ii][2], acc2[ii][3]};
        *(float4*)&sB[kloc + ii][tx * 4] = v;
      }
    }
    __syncthreads();
    {
      int c = tid >> 2, d8 = (tid & 3) * 8;
      float t0 = sB[d8 + 0][c], t1 = sB[d8 + 1][c], t2 = sB[d8 + 2][c], t3 = sB[d8 + 3][c];
      float t4 = sB[d8 + 4][c], t5 = sB[d8 + 5][c], t6 = sB[d8 + 6][c], t7 = sB[d8 + 7][c];
      float* dst = Wm + ((size_t)(s * NCOUT) + cb + c) * ND + rb + kk * 32 + d8;
      float4 w0 = {t0, t1, t2, t3}, w1 = {t4, t5, t6, t7};
      *(float4*)dst = w0;
      *(float4*)(dst + 4) = w1;
    }
  }
}

__global__ __launch_bounds__(256) void k_finalize(const float* __restrict__ logd,
                                                  const float* __restrict__ pp,
                                                  float* __restrict__ out) {
  int s = blockIdx.x, tid = threadIdx.x;
  __shared__ float r0[256];
  float l = 0.f;
  for (int i = tid; i < ND; i += 256) l += logd[s * ND + i];
  r0[tid] = l;
  __syncthreads();
  for (int off = 128; off; off >>= 1) {
    if (tid < off) r0[tid] += r0[tid + off];
    __syncthreads();
  }
  if (tid == 0) {
    float logdet = 2.0f * r0[0];
    out[s] = 0.5f * (pp[s] - pp[4 + s]) - 128.0f * logdet;
  }
}

// ---------------- launcher ----------------
extern "C" void kernel_launch(void* const* d_in, const int* in_sizes, int n_in,
                              void* d_out, int out_size, void* d_ws, size_t ws_size,
                              hipStream_t stream) {
  const float* X = (const float*)d_in[0];
  const float* u = (const float*)d_in[1];
  const float* lp = (const float*)d_in[2];
  const float* Z = (const float*)d_in[3];
  float* out = (float*)d_out;

  float* ws = (float*)d_ws;
  float* sp    = ws;                                   // 64
  float* invd  = sp + 64;                              // 4608
  float* logd  = invd + (size_t)NS * ND;               // 4608
  float* pp    = logd + (size_t)NS * ND;               // 64 (8 used)
  int*   flags = (int*)(pp + 64);                      // 512 ints (288 used)
  float* iD    = (float*)(flags + 512);                // 4*9*16384
  float* Xf    = iD + (size_t)NS * 9 * 16384;          // 4*1152*256
  float* Xb    = Xf + (size_t)NS * ND * NCOUT;         // 4*1152*256
  float* prec  = Xb + (size_t)NS * ND * NCOUT;         // 4*1152*1152
  float* XLY   = prec + (size_t)NS * D2;               // 4*1152*256
  unsigned short* Phi = (unsigned short*)(XLY + (size_t)NS * ND * NCOUT);
  unsigned short* Plo = Phi + (size_t)NS * ND * NK;
  unsigned short* Yhi = Plo + (size_t)NS * ND * NK;
  unsigned short* Ylo = Yhi + (size_t)NCOUT * NK;

  hipMemsetAsync(flags, 0, 512 * sizeof(int), stream);
  k_sqrtp<<<1, 64, 0, stream>>>(lp, sp, pp);
  k_patches<<<dim3(ND, NS), 256, 0, stream>>>(X, sp, Phi, Plo);
  k_ytt<<<NCOUT, 256, 0, stream>>>(u, sp, Yhi, Ylo);
  k_gemm_mfma<<<dim3(11, 9, NS), 256, 0, stream>>>(Phi, Plo, Yhi, Ylo, prec, XLY);

  for (int q = 0; q < 18; ++q) {
    k_chol_panel<<<dim3(NS, 18 - q), 64, 0, stream>>>(prec, invd, logd, q);
    if (q < 17) {
      int m = 17 - q;
      k_chol_update<<<dim3(m, m, NS), 256, 0, stream>>>(prec, q);
    }
  }
  k_invd128<<<dim3(9, NS), 64, 0, stream>>>(prec, iD);

  k_fsolve<<<dim3(9, 4, NS), 256, 0, stream>>>(prec, iD, XLY, Xf, flags);
  k_bsolve<<<dim3(9, 4, NS), 256, 0, stream>>>(prec, iD, Xf, Z, Xb, out, pp, flags);
  k_finalize<<<NS, 256, 0, stream>>>(logd, pp, out + (size_t)NS * NCOUT * ND);
}

// Round 5
// 2160.204 us; speedup vs baseline: 1.2388x; 1.2388x over previous
//
#include <hip/hip_runtime.h>
#include <math.h>

#define NS 4
#define NB 32
#define CIN 128
#define NCOUT 256
#define HWN 256
#define ND 1152
#define NK 8192   // NB*HWN
static const size_t D2 = (size_t)ND * ND;

typedef __attribute__((ext_vector_type(8))) short bf16x8;
typedef __attribute__((ext_vector_type(4))) float f32x4;

static __device__ inline unsigned short f2bf(float x) {
  unsigned int u = __float_as_uint(x);
  unsigned int r = (u + 0x7fffu + ((u >> 16) & 1u)) >> 16;
  return (unsigned short)r;
}
static __device__ inline float bf2f(unsigned short h) {
  return __uint_as_float(((unsigned int)h) << 16);
}

// ---------------- small prep kernels ----------------

__global__ void k_sqrtp(const float* __restrict__ lp, float* __restrict__ sp,
                        float* __restrict__ pp) {
  int b = threadIdx.x;
  if (b < NB) sp[b] = expf(0.5f * lp[b]);
  if (b < 8) pp[b] = 0.f;
}

__global__ __launch_bounds__(256) void k_patches(const float* __restrict__ X,
                                                 const float* __restrict__ sp,
                                                 unsigned short* __restrict__ Phi,
                                                 unsigned short* __restrict__ Plo) {
  int d = blockIdx.x, s = blockIdx.y, p = threadIdx.x;
  int c = d / 9, r = d % 9, ky = r / 3, kx = r % 3;
  int yy = (p >> 4) + ky - 1, xx = (p & 15) + kx - 1;
  bool ok = (yy >= 0 && yy < 16 && xx >= 0 && xx < 16);
  int xoff = yy * 16 + xx;
  size_t base = ((size_t)s * ND + d) * NK + p;
  for (int b = 0; b < NB; ++b) {
    float v = 0.f;
    if (ok) v = X[((size_t)(s * NB + b) * CIN + c) * HWN + xoff] * sp[b];
    unsigned short h = f2bf(v);
    Phi[base + b * HWN] = h;
    Plo[base + b * HWN] = f2bf(v - bf2f(h));
  }
}

__global__ __launch_bounds__(256) void k_ytt(const float* __restrict__ u,
                                             const float* __restrict__ sp,
                                             unsigned short* __restrict__ Yhi,
                                             unsigned short* __restrict__ Ylo) {
  int c = blockIdx.x, p = threadIdx.x;
  for (int b = 0; b < NB; ++b) {
    float v = sp[b] * u[((size_t)b * NCOUT + c) * HWN + p];
    unsigned short h = f2bf(v);
    size_t idx = (size_t)c * NK + b * HWN + p;
    Yhi[idx] = h;
    Ylo[idx] = f2bf(v - bf2f(h));
  }
}

// ---------------- bf16x3 MFMA fused XLX (lower 128-tiles) + XLY ----------------
__global__ __launch_bounds__(256) void k_gemm_mfma(
    const unsigned short* __restrict__ Phi, const unsigned short* __restrict__ Plo,
    const unsigned short* __restrict__ Yhi, const unsigned short* __restrict__ Ylo,
    float* __restrict__ prec, float* __restrict__ XLY) {
  int jt = blockIdx.x, it = blockIdx.y, s = blockIdx.z;
  bool isX = (jt <= it);
  if (!isX && jt < 9) return;
  int i0 = it * 128;
  int j0;
  const unsigned short *Bh, *Bl;
  if (isX) {
    j0 = jt * 128;
    Bh = Phi + ((size_t)s * ND + j0) * NK;
    Bl = Plo + ((size_t)s * ND + j0) * NK;
  } else {
    j0 = (jt - 9) * 128;
    Bh = Yhi + (size_t)j0 * NK;
    Bl = Ylo + (size_t)j0 * NK;
  }
  const unsigned short* Ah = Phi + ((size_t)s * ND + i0) * NK;
  const unsigned short* Al = Plo + ((size_t)s * ND + i0) * NK;

  __shared__ unsigned short sAh[4096], sAl[4096], sBh[4096], sBl[4096];
  int tid = threadIdx.x, wave = tid >> 6, lane = tid & 63;
  int wr = wave >> 1, wc = wave & 1;

  f32x4 zero = {0.f, 0.f, 0.f, 0.f};
  f32x4 acc[4][4];
#pragma unroll
  for (int m = 0; m < 4; ++m)
#pragma unroll
    for (int n = 0; n < 4; ++n) acc[m][n] = zero;

  const unsigned short* srcs[4] = {Ah, Al, Bh, Bl};
  unsigned short* dsts[4] = {sAh, sAl, sBh, sBl};
  int r0l = lane >> 2;
  int ke = (lane & 3) * 8;
  int arow0 = wr * 64 + (lane & 15);
  int brow0 = wc * 64 + (lane & 15);
  int koff = (lane >> 4) * 8;

  for (int k0 = 0; k0 < NK; k0 += 32) {
    __syncthreads();
#pragma unroll
    for (int f = 0; f < 4; ++f) {
#pragma unroll
      for (int cc = 0; cc < 2; ++cc) {
        int c = wave * 2 + cc;
        const unsigned short* g = srcs[f] + (size_t)(c * 16 + r0l) * NK + k0 + ke;
        unsigned short* l = dsts[f] + c * 512;
        __builtin_amdgcn_global_load_lds(
            (const __attribute__((address_space(1))) void*)g,
            (__attribute__((address_space(3))) void*)l, 16, 0, 0);
      }
    }
    __syncthreads();
    bf16x8 ah[4], al[4], bh[4], bl[4];
#pragma unroll
    for (int m = 0; m < 4; ++m) {
      int off = (arow0 + m * 16) * 32 + koff;
      ah[m] = *(const bf16x8*)&sAh[off];
      al[m] = *(const bf16x8*)&sAl[off];
    }
#pragma unroll
    for (int n = 0; n < 4; ++n) {
      int off = (brow0 + n * 16) * 32 + koff;
      bh[n] = *(const bf16x8*)&sBh[off];
      bl[n] = *(const bf16x8*)&sBl[off];
    }
#pragma unroll
    for (int m = 0; m < 4; ++m)
#pragma unroll
      for (int n = 0; n < 4; ++n) {
        acc[m][n] = __builtin_amdgcn_mfma_f32_16x16x32_bf16(ah[m], bh[n], acc[m][n], 0, 0, 0);
        acc[m][n] = __builtin_amdgcn_mfma_f32_16x16x32_bf16(ah[m], bl[n], acc[m][n], 0, 0, 0);
        acc[m][n] = __builtin_amdgcn_mfma_f32_16x16x32_bf16(al[m], bh[n], acc[m][n], 0, 0, 0);
      }
  }

  if (isX) {
    float* base = prec + (size_t)s * D2;
#pragma unroll
    for (int m = 0; m < 4; ++m) {
      int row = i0 + wr * 64 + m * 16 + (lane >> 4) * 4;
#pragma unroll
      for (int n = 0; n < 4; ++n) {
        int col = j0 + wc * 64 + n * 16 + (lane & 15);
        float* cp = base + (size_t)row * ND + col;
#pragma unroll
        for (int r = 0; r < 4; ++r) {
          float v = acc[m][n][r];
          if (row + r == col) v += 1.f;
          cp[(size_t)r * ND] = v;
        }
      }
    }
  } else {
    float* base = XLY + (size_t)s * ND * NCOUT;
#pragma unroll
    for (int m = 0; m < 4; ++m) {
      int row = i0 + wr * 64 + m * 16 + (lane >> 4) * 4;
#pragma unroll
      for (int n = 0; n < 4; ++n) {
        int col = j0 + wc * 64 + n * 16 + (lane & 15);
        float* cp = base + (size_t)row * NCOUT + col;
#pragma unroll
        for (int r = 0; r < 4; ++r) cp[(size_t)r * NCOUT] = acc[m][n][r];
      }
    }
  }
}

// ---------------- blocked Cholesky, NB=64 (unchanged) ----------------
__global__ __launch_bounds__(64) void k_chol_panel(float* __restrict__ L,
                                                   float* __restrict__ invd,
                                                   float* __restrict__ logd, int q) {
  const int s = blockIdx.x;
  const int strip = blockIdx.y;
  const int lane = threadIdx.x;
  const int j0 = q * 64;
  float* Ls = L + (size_t)s * D2;
  __shared__ float tile[64][65];
  for (int r = 0; r < 64; ++r) tile[r][lane] = Ls[(size_t)(j0 + r) * ND + j0 + lane];
  __syncthreads();
  float a[64];
#pragma unroll
  for (int t = 0; t < 64; ++t) a[t] = tile[lane][t];
  float diagv = 1.f;
#pragma unroll
  for (int j = 0; j < 64; ++j) {
    float dj = __shfl(a[j], j, 64);
    float rinv = 1.0f / sqrtf(dj);
    a[j] *= rinv;
    if (lane == j) diagv = a[j];
#pragma unroll
    for (int t = j + 1; t < 64; ++t) {
      float ltj = __shfl(a[j], t, 64);
      a[t] = fmaf(-a[j], ltj, a[t]);
    }
  }
  if (strip == 0) {
    __syncthreads();
#pragma unroll
    for (int t = 0; t < 64; ++t) tile[lane][t] = a[t];
    __syncthreads();
    for (int r = 0; r < 64; ++r) Ls[(size_t)(j0 + r) * ND + j0 + lane] = tile[r][lane];
    invd[s * ND + j0 + lane] = 1.0f / diagv;
    logd[s * ND + j0 + lane] = logf(diagv);
  } else {
    const int r0 = j0 + 64 * strip;
    __syncthreads();
    for (int r = 0; r < 64; ++r) tile[r][lane] = Ls[(size_t)(r0 + r) * ND + j0 + lane];
    __syncthreads();
    float b[64];
#pragma unroll
    for (int t = 0; t < 64; ++t) b[t] = tile[lane][t];
#pragma unroll
    for (int j = 0; j < 64; ++j) {
      float dj = __shfl(a[j], j, 64);
      b[j] *= (1.0f / dj);
#pragma unroll
      for (int t = j + 1; t < 64; ++t) {
        float ltj = __shfl(a[j], t, 64);
        b[t] = fmaf(-b[j], ltj, b[t]);
      }
    }
    __syncthreads();
#pragma unroll
    for (int t = 0; t < 64; ++t) tile[lane][t] = b[t];
    __syncthreads();
    for (int r = 0; r < 64; ++r) Ls[(size_t)(r0 + r) * ND + j0 + lane] = tile[r][lane];
  }
}

__global__ __launch_bounds__(256) void k_chol_update(float* __restrict__ L, int q) {
  int ti = blockIdx.x, tj = blockIdx.y, s = blockIdx.z;
  if (ti < tj) return;
  int j0 = q * 64;
  int r0 = j0 + 64 + ti * 64;
  int c0 = j0 + 64 + tj * 64;
  float* Ls = L + (size_t)s * D2;
  __shared__ float At[64][64];
  __shared__ float Bt[64][64];
  int tid = threadIdx.x;
  {
    int a = tid >> 2, km = (tid & 3) * 4;
#pragma unroll
    for (int m = 0; m < 4; ++m) {
      float4 v = *(const float4*)(Ls + (size_t)(r0 + a) * ND + j0 + km + m * 16);
      At[km + m * 16 + 0][a] = v.x;
      At[km + m * 16 + 1][a] = v.y;
      At[km + m * 16 + 2][a] = v.z;
      At[km + m * 16 + 3][a] = v.w;
      float4 w = *(const float4*)(Ls + (size_t)(c0 + a) * ND + j0 + km + m * 16);
      Bt[km + m * 16 + 0][a] = w.x;
      Bt[km + m * 16 + 1][a] = w.y;
      Bt[km + m * 16 + 2][a] = w.z;
      Bt[km + m * 16 + 3][a] = w.w;
    }
  }
  __syncthreads();
  int tx = tid & 15, ty = tid >> 4;
  float acc[4][4] = {};
#pragma unroll
  for (int k = 0; k < 64; ++k) {
    float4 a4 = *(const float4*)&At[k][ty * 4];
    float4 b4 = *(const float4*)&Bt[k][tx * 4];
    float ar[4] = {a4.x, a4.y, a4.z, a4.w};
    float br[4] = {b4.x, b4.y, b4.z, b4.w};
#pragma unroll
    for (int r = 0; r < 4; ++r)
#pragma unroll
      for (int e = 0; e < 4; ++e) acc[r][e] = fmaf(ar[r], br[e], acc[r][e]);
  }
#pragma unroll
  for (int r = 0; r < 4; ++r) {
    float* cp = Ls + (size_t)(r0 + ty * 4 + r) * ND + c0 + tx * 4;
    float4 c = *(const float4*)cp;
    c.x -= acc[r][0]; c.y -= acc[r][1]; c.z -= acc[r][2]; c.w -= acc[r][3];
    *(float4*)cp = c;
  }
}

// ---------------- invert 128x128 diag blocks (wave-parallel) ----------------
// [A 0; B C]^-1 = [iA 0; -iC*B*iA, iC]
// waves 0/1: shuffle-substitution inversion of A / C in registers (lane = col);
// waves 2/3: stage B^T; then 256-thr LDS GEMMs for T = B@iA and G = -iC@T.
__global__ __launch_bounds__(256) void k_invd128(const float* __restrict__ L,
                                                 float* __restrict__ iD) {
  int q = blockIdx.x, s = blockIdx.y;
  int tid = threadIdx.x, lane = tid & 63, w = tid >> 6;
  const float* Ls = L + (size_t)s * D2;
  float* out = iD + ((size_t)(s * 9 + q)) * 16384;
  int b0 = q * 128;
  __shared__ float inv0[64][65];   // iA[i][j]
  __shared__ float invCt[64][65];  // invCt[j][i] = iC[i][j]
  __shared__ float Bt[64][65];     // Bt[k][i] = L21[i][k]
  __shared__ float Tl[64][65];     // T[i][j] = (B @ iA)[i][j]

  if (w < 2) {
    const float* base = Ls + (size_t)(b0 + w * 64) * ND + b0 + w * 64;
    float lcol[64], x[64];
#pragma unroll
    for (int i = 0; i < 64; ++i) {
      lcol[i] = base[(size_t)i * ND + lane];  // column 'lane' of triangle
      x[i] = (i == lane) ? 1.f : 0.f;
    }
#pragma unroll
    for (int j = 0; j < 64; ++j) {
      float ljj = __shfl(lcol[j], j, 64);
      float xj = x[j] / ljj;
      x[j] = xj;
#pragma unroll
      for (int i = j + 1; i < 64; ++i) {
        float lij = __shfl(lcol[i], j, 64);
        x[i] = fmaf(-lij, xj, x[i]);
      }
    }
    if (w == 0) {
#pragma unroll
      for (int i = 0; i < 64; ++i) inv0[i][lane] = x[i];
    } else {
#pragma unroll
      for (int i = 0; i < 64; ++i) invCt[lane][i] = x[i];
    }
  } else {
    int t = tid - 128;               // 0..127
    int i = t & 63, kh = (t >> 6) * 32;
    const float* src = Ls + (size_t)(b0 + 64 + i) * ND + b0 + kh;
#pragma unroll
    for (int m = 0; m < 8; ++m) {
      float4 v = *(const float4*)(src + m * 4);
      Bt[kh + m * 4 + 0][i] = v.x;
      Bt[kh + m * 4 + 1][i] = v.y;
      Bt[kh + m * 4 + 2][i] = v.z;
      Bt[kh + m * 4 + 3][i] = v.w;
    }
  }
  __syncthreads();

  int tx = tid & 15, ty = tid >> 4;
  // GEMM1: T[i][j] = sum_k Bt[k][i] * inv0[k][j]
  float acc[4][4] = {};
#pragma unroll
  for (int k = 0; k < 64; ++k) {
    float a4[4], b4[4];
#pragma unroll
    for (int e = 0; e < 4; ++e) { a4[e] = Bt[k][ty * 4 + e]; b4[e] = inv0[k][tx * 4 + e]; }
#pragma unroll
    for (int r = 0; r < 4; ++r)
#pragma unroll
      for (int e = 0; e < 4; ++e) acc[r][e] = fmaf(a4[r], b4[e], acc[r][e]);
  }
#pragma unroll
  for (int r = 0; r < 4; ++r)
#pragma unroll
    for (int e = 0; e < 4; ++e) Tl[ty * 4 + r][tx * 4 + e] = acc[r][e];
  __syncthreads();
  // GEMM2: G[i][j] = sum_k invCt[k][i] * Tl[k][j]  (= (iC @ T)[i][j])
  float acc2[4][4] = {};
#pragma unroll
  for (int k = 0; k < 64; ++k) {
    float a4[4], b4[4];
#pragma unroll
    for (int e = 0; e < 4; ++e) { a4[e] = invCt[k][ty * 4 + e]; b4[e] = Tl[k][tx * 4 + e]; }
#pragma unroll
    for (int r = 0; r < 4; ++r)
#pragma unroll
      for (int e = 0; e < 4; ++e) acc2[r][e] = fmaf(a4[r], b4[e], acc2[r][e]);
  }
  // write: rows 0..63 = [iA | 0]
  {
    int rrow = tid >> 2, cc = (tid & 3) * 32;
    float* o = out + rrow * 128 + cc;
    if (cc < 64) {
#pragma unroll
      for (int m = 0; m < 8; ++m) {
        float4 v = {inv0[rrow][cc + m * 4 + 0], inv0[rrow][cc + m * 4 + 1],
                    inv0[rrow][cc + m * 4 + 2], inv0[rrow][cc + m * 4 + 3]};
        *(float4*)(o + m * 4) = v;
      }
    } else {
      float4 z = {0.f, 0.f, 0.f, 0.f};
#pragma unroll
      for (int m = 0; m < 8; ++m) *(float4*)(o + m * 4) = z;
    }
  }
  // rows 64..127, cols 0..63 = -G (from registers)
#pragma unroll
  for (int r = 0; r < 4; ++r) {
    float4 v = {-acc2[r][0], -acc2[r][1], -acc2[r][2], -acc2[r][3]};
    *(float4*)(out + (size_t)(64 + ty * 4 + r) * 128 + tx * 4) = v;
  }
  // rows 64..127, cols 64..127 = iC
  {
    int i = tid >> 2, jc = (tid & 3) * 16;
#pragma unroll
    for (int m = 0; m < 4; ++m) {
      float4 v = {invCt[jc + m * 4 + 0][i], invCt[jc + m * 4 + 1][i],
                  invCt[jc + m * 4 + 2][i], invCt[jc + m * 4 + 3][i]};
      *(float4*)(out + (size_t)(64 + i) * 128 + 64 + jc + m * 4) = v;
    }
  }
}

// ---------------- persistent flag-synced forward solve ----------------
__global__ __launch_bounds__(256) void k_fsolve(const float* __restrict__ L,
                                                const float* __restrict__ iD,
                                                const float* __restrict__ Bsrc,
                                                float* __restrict__ Xf,
                                                int* __restrict__ flags) {
  int r = blockIdx.x, ct = blockIdx.y, s = blockIdx.z;
  int rb = r * 128, cb = ct * 64;
  const float* Ls = L + (size_t)s * D2;
  const float* Dq = iD + ((size_t)(s * 9 + r)) * 16384;
  const float* Bs = Bsrc + (size_t)s * ND * NCOUT;
  float* Xs = Xf + (size_t)s * ND * NCOUT;
  int fbase = (s * 4 + ct) * 9;

  __shared__ float sA[32][132];
  __shared__ float sB[32][68];
  int tid = threadIdx.x, tx = tid & 15, ty = tid >> 4;
  float acc[8][4];
#pragma unroll
  for (int ii = 0; ii < 8; ++ii) {
    float4 v = *(const float4*)(Bs + (size_t)(rb + ty * 8 + ii) * NCOUT + cb + tx * 4);
    acc[ii][0] = v.x; acc[ii][1] = v.y; acc[ii][2] = v.z; acc[ii][3] = v.w;
  }
  for (int q = 0; q < r; ++q) {
    if (tid == 0) {
      while (__hip_atomic_load(&flags[fbase + q], __ATOMIC_RELAXED,
                               __HIP_MEMORY_SCOPE_AGENT) == 0)
        __builtin_amdgcn_s_sleep(2);
      (void)__hip_atomic_load(&flags[fbase + q], __ATOMIC_ACQUIRE,
                              __HIP_MEMORY_SCOPE_AGENT);
    }
    __syncthreads();
    int qb = q * 128;
    for (int kk = 0; kk < 4; ++kk) {
      __syncthreads();
      {  // sA[k][i] = L[rb+i][qb+kk*32+k]
        int i = tid >> 1, kb = (tid & 1) * 16;
        const float* src = Ls + (size_t)(rb + i) * ND + qb + kk * 32 + kb;
#pragma unroll
        for (int m = 0; m < 4; ++m) {
          float4 v = *(const float4*)(src + m * 4);
          sA[kb + m * 4 + 0][i] = v.x;
          sA[kb + m * 4 + 1][i] = v.y;
          sA[kb + m * 4 + 2][i] = v.z;
          sA[kb + m * 4 + 3][i] = v.w;
        }
      }
      {  // sB[k][j] = Xq[qb+kk*32+k][cb+j] (plain vectorized)
        int k = tid >> 3, jb = (tid & 7) * 8;
        const float* src = Xs + (size_t)(qb + kk * 32 + k) * NCOUT + cb + jb;
        float4 v0 = *(const float4*)src;
        float4 v1 = *(const float4*)(src + 4);
        *(float4*)&sB[k][jb] = v0;
        *(float4*)&sB[k][jb + 4] = v1;
      }
      __syncthreads();
#pragma unroll
      for (int k = 0; k < 32; ++k) {
        float4 a0 = *(const float4*)&sA[k][ty * 8];
        float4 a1 = *(const float4*)&sA[k][ty * 8 + 4];
        float4 b0 = *(const float4*)&sB[k][tx * 4];
        float a[8] = {a0.x, a0.y, a0.z, a0.w, a1.x, a1.y, a1.z, a1.w};
        float b[4] = {b0.x, b0.y, b0.z, b0.w};
#pragma unroll
        for (int ii = 0; ii < 8; ++ii)
#pragma unroll
          for (int j = 0; j < 4; ++j) acc[ii][j] = fmaf(-a[ii], b[j], acc[ii][j]);
      }
    }
  }
  // diag: acc2 = iD[r] @ acc
  float acc2[8][4] = {};
  for (int kk = 0; kk < 4; ++kk) {
    __syncthreads();
    if ((ty >> 2) == kk) {
      int kloc = ty * 8 - kk * 32;
#pragma unroll
      for (int ii = 0; ii < 8; ++ii) {
        float4 v = {acc[ii][0], acc[ii][1], acc[ii][2], acc[ii][3]};
        *(float4*)&sB[kloc + ii][tx * 4] = v;
      }
    }
    {  // sA[k][i] = iD[i][kk*32+k]
      int i = tid >> 1, kb = (tid & 1) * 16;
      const float* src = Dq + (size_t)i * 128 + kk * 32 + kb;
#pragma unroll
      for (int m = 0; m < 4; ++m) {
        float4 v = *(const float4*)(src + m * 4);
        sA[kb + m * 4 + 0][i] = v.x;
        sA[kb + m * 4 + 1][i] = v.y;
        sA[kb + m * 4 + 2][i] = v.z;
        sA[kb + m * 4 + 3][i] = v.w;
      }
    }
    __syncthreads();
#pragma unroll
    for (int k = 0; k < 32; ++k) {
      float4 a0 = *(const float4*)&sA[k][ty * 8];
      float4 a1 = *(const float4*)&sA[k][ty * 8 + 4];
      float4 b0 = *(const float4*)&sB[k][tx * 4];
      float a[8] = {a0.x, a0.y, a0.z, a0.w, a1.x, a1.y, a1.z, a1.w};
      float b[4] = {b0.x, b0.y, b0.z, b0.w};
#pragma unroll
      for (int ii = 0; ii < 8; ++ii)
#pragma unroll
        for (int j = 0; j < 4; ++j) acc2[ii][j] = fmaf(a[ii], b[j], acc2[ii][j]);
    }
  }
  // publish (plain stores + fence + flag release)
#pragma unroll
  for (int ii = 0; ii < 8; ++ii) {
    float4 v = {acc2[ii][0], acc2[ii][1], acc2[ii][2], acc2[ii][3]};
    *(float4*)(Xs + (size_t)(rb + ty * 8 + ii) * NCOUT + cb + tx * 4) = v;
  }
  __threadfence();
  __syncthreads();
  if (tid == 0)
    __hip_atomic_store(&flags[fbase + r], 1, __ATOMIC_RELEASE,
                       __HIP_MEMORY_SCOPE_AGENT);
}

// ---------------- persistent flag-synced backward solve (fused addz + writewm) ----------------
__global__ __launch_bounds__(256) void k_bsolve(const float* __restrict__ L,
                                                const float* __restrict__ iD,
                                                const float* __restrict__ Xf,
                                                const float* __restrict__ Z,
                                                float* __restrict__ Xb,
                                                float* __restrict__ Wm,
                                                float* __restrict__ pp,
                                                int* __restrict__ flags) {
  int r = 8 - blockIdx.x, ct = blockIdx.y, s = blockIdx.z;
  int rb = r * 128, cb = ct * 64;
  const float* Ls = L + (size_t)s * D2;
  const float* Dq = iD + ((size_t)(s * 9 + r)) * 16384;
  const float* Xfs = Xf + (size_t)s * ND * NCOUT;
  float* Xs = Xb + (size_t)s * ND * NCOUT;
  int fbase = 144 + (s * 4 + ct) * 9;

  __shared__ float sA[32][132];
  __shared__ float sB[32][68];
  __shared__ float red[8];
  int tid = threadIdx.x, tx = tid & 15, ty = tid >> 4;
  int wave = tid >> 6, lane = tid & 63;

  float acc[8][4];
#pragma unroll
  for (int ii = 0; ii < 8; ++ii) {
    float4 v = *(const float4*)(Xfs + (size_t)(rb + ty * 8 + ii) * NCOUT + cb + tx * 4);
    acc[ii][0] = v.x; acc[ii][1] = v.y; acc[ii][2] = v.z; acc[ii][3] = v.w;
  }
  // add Z^T tile + zsum
  float zp = 0.f;
  for (int kk = 0; kk < 4; ++kk) {
    __syncthreads();
    {
      int c = tid >> 2, d8 = (tid & 3) * 8;
      const float* src = Z + ((size_t)(s * NCOUT) + cb + c) * ND + rb + kk * 32 + d8;
      float4 v0 = *(const float4*)src;
      float4 v1 = *(const float4*)(src + 4);
      sA[d8 + 0][c] = v0.x; sA[d8 + 1][c] = v0.y; sA[d8 + 2][c] = v0.z; sA[d8 + 3][c] = v0.w;
      sA[d8 + 4][c] = v1.x; sA[d8 + 5][c] = v1.y; sA[d8 + 6][c] = v1.z; sA[d8 + 7][c] = v1.w;
      zp += v0.x * v0.x + v0.y * v0.y + v0.z * v0.z + v0.w * v0.w;
      zp += v1.x * v1.x + v1.y * v1.y + v1.z * v1.z + v1.w * v1.w;
    }
    __syncthreads();
    if ((ty >> 2) == kk) {
      int kloc = ty * 8 - kk * 32;
#pragma unroll
      for (int ii = 0; ii < 8; ++ii) {
        float4 v = *(const float4*)&sA[kloc + ii][tx * 4];
        acc[ii][0] += v.x; acc[ii][1] += v.y; acc[ii][2] += v.z; acc[ii][3] += v.w;
      }
    }
  }
#pragma unroll
  for (int m2 = 32; m2 >= 1; m2 >>= 1) zp += __shfl_xor(zp, m2, 64);
  if (lane == 0) red[wave] = zp;
  __syncthreads();
  if (tid == 0) atomicAdd(pp + s, red[0] + red[1] + red[2] + red[3]);

  for (int q = 8; q > r; --q) {
    if (tid == 0) {
      while (__hip_atomic_load(&flags[fbase + q], __ATOMIC_RELAXED,
                               __HIP_MEMORY_SCOPE_AGENT) == 0)
        __builtin_amdgcn_s_sleep(2);
      (void)__hip_atomic_load(&flags[fbase + q], __ATOMIC_ACQUIRE,
                              __HIP_MEMORY_SCOPE_AGENT);
    }
    __syncthreads();
    int qb = q * 128;
    for (int kk = 0; kk < 4; ++kk) {
      __syncthreads();
      {  // sA[k][i] = L[qb+kk*32+k][rb+i]  (natural row copy)
        int k = tid >> 3, ib = (tid & 7) * 16;
        const float* src = Ls + (size_t)(qb + kk * 32 + k) * ND + rb + ib;
#pragma unroll
        for (int m = 0; m < 4; ++m)
          *(float4*)&sA[k][ib + m * 4] = *(const float4*)(src + m * 4);
      }
      {  // sB[k][j] = Xq (plain vectorized)
        int k = tid >> 3, jb = (tid & 7) * 8;
        const float* src = Xs + (size_t)(qb + kk * 32 + k) * NCOUT + cb + jb;
        float4 v0 = *(const float4*)src;
        float4 v1 = *(const float4*)(src + 4);
        *(float4*)&sB[k][jb] = v0;
        *(float4*)&sB[k][jb + 4] = v1;
      }
      __syncthreads();
#pragma unroll
      for (int k = 0; k < 32; ++k) {
        float4 a0 = *(const float4*)&sA[k][ty * 8];
        float4 a1 = *(const float4*)&sA[k][ty * 8 + 4];
        float4 b0 = *(const float4*)&sB[k][tx * 4];
        float a[8] = {a0.x, a0.y, a0.z, a0.w, a1.x, a1.y, a1.z, a1.w};
        float b[4] = {b0.x, b0.y, b0.z, b0.w};
#pragma unroll
        for (int ii = 0; ii < 8; ++ii)
#pragma unroll
          for (int j = 0; j < 4; ++j) acc[ii][j] = fmaf(-a[ii], b[j], acc[ii][j]);
      }
    }
  }
  // diag: acc2 = iD[r]^T @ acc
  float acc2[8][4] = {};
  for (int kk = 0; kk < 4; ++kk) {
    __syncthreads();
    if ((ty >> 2) == kk) {
      int kloc = ty * 8 - kk * 32;
#pragma unroll
      for (int ii = 0; ii < 8; ++ii) {
        float4 v = {acc[ii][0], acc[ii][1], acc[ii][2], acc[ii][3]};
        *(float4*)&sB[kloc + ii][tx * 4] = v;
      }
    }
    {
      int k = tid >> 3, ib = (tid & 7) * 16;
      const float* src = Dq + (size_t)(kk * 32 + k) * 128 + ib;
#pragma unroll
      for (int m = 0; m < 4; ++m)
        *(float4*)&sA[k][ib + m * 4] = *(const float4*)(src + m * 4);
    }
    __syncthreads();
#pragma unroll
    for (int k = 0; k < 32; ++k) {
      float4 a0 = *(const float4*)&sA[k][ty * 8];
      float4 a1 = *(const float4*)&sA[k][ty * 8 + 4];
      float4 b0 = *(const float4*)&sB[k][tx * 4];
      float a[8] = {a0.x, a0.y, a0.z, a0.w, a1.x, a1.y, a1.z, a1.w};
      float b[4] = {b0.x, b0.y, b0.z, b0.w};
#pragma unroll
      for (int ii = 0; ii < 8; ++ii)
#pragma unroll
        for (int j = 0; j < 4; ++j) acc2[ii][j] = fmaf(a[ii], b[j], acc2[ii][j]);
    }
  }
  // publish X (plain stores + fence + flag release)
#pragma unroll
  for (int ii = 0; ii < 8; ++ii) {
    float4 v = {acc2[ii][0], acc2[ii][1], acc2[ii][2], acc2[ii][3]};
    *(float4*)(Xs + (size_t)(rb + ty * 8 + ii) * NCOUT + cb + tx * 4) = v;
  }
  __threadfence();
  __syncthreads();
  if (tid == 0)
    __hip_atomic_store(&flags[fbase + r], 1, __ATOMIC_RELEASE,
                       __HIP_MEMORY_SCOPE_AGENT);
  // wsum
  float wp = 0.f;
#pragma unroll
  for (int ii = 0; ii < 8; ++ii)
#pragma unroll
    for (int j = 0; j < 4; ++j) wp += acc2[ii][j] * acc2[ii][j];
#pragma unroll
  for (int m2 = 32; m2 >= 1; m2 >>= 1) wp += __shfl_xor(wp, m2, 64);
  __syncthreads();
  if (lane == 0) red[wave] = wp;
  __syncthreads();
  if (tid == 0) atomicAdd(pp + 4 + s, red[0] + red[1] + red[2] + red[3]);
  // Wm[s][c][d] = acc2[d][c]
  for (int kk = 0; kk < 4; ++kk) {
    __syncthreads();
    if ((ty >> 2) == kk) {
      int kloc = ty * 8 - kk * 32;
#pragma unroll
      for (int ii = 0; ii < 8; ++ii) {
        float4 v = {acc2[ii][0], acc2[ii][1], acc2[ii][2], acc2[ii][3]};
        *(float4*)&sB[kloc + ii][tx * 4] = v;
      }
    }
    __syncthreads();
    {
      int c = tid >> 2, d8 = (tid & 3) * 8;
      float t0 = sB[d8 + 0][c], t1 = sB[d8 + 1][c], t2 = sB[d8 + 2][c], t3 = sB[d8 + 3][c];
      float t4 = sB[d8 + 4][c], t5 = sB[d8 + 5][c], t6 = sB[d8 + 6][c], t7 = sB[d8 + 7][c];
      float* dst = Wm + ((size_t)(s * NCOUT) + cb + c) * ND + rb + kk * 32 + d8;
      float4 w0 = {t0, t1, t2, t3}, w1 = {t4, t5, t6, t7};
      *(float4*)dst = w0;
      *(float4*)(dst + 4) = w1;
    }
  }
}

__global__ __launch_bounds__(256) void k_finalize(const float* __restrict__ logd,
                                                  const float* __restrict__ pp,
                                                  float* __restrict__ out) {
  int s = blockIdx.x, tid = threadIdx.x;
  __shared__ float r0[256];
  float l = 0.f;
  for (int i = tid; i < ND; i += 256) l += logd[s * ND + i];
  r0[tid] = l;
  __syncthreads();
  for (int off = 128; off; off >>= 1) {
    if (tid < off) r0[tid] += r0[tid + off];
    __syncthreads();
  }
  if (tid == 0) {
    float logdet = 2.0f * r0[0];
    out[s] = 0.5f * (pp[s] - pp[4 + s]) - 128.0f * logdet;
  }
}

// ---------------- launcher ----------------
extern "C" void kernel_launch(void* const* d_in, const int* in_sizes, int n_in,
                              void* d_out, int out_size, void* d_ws, size_t ws_size,
                              hipStream_t stream) {
  const float* X = (const float*)d_in[0];
  const float* u = (const float*)d_in[1];
  const float* lp = (const float*)d_in[2];
  const float* Z = (const float*)d_in[3];
  float* out = (float*)d_out;

  float* ws = (float*)d_ws;
  float* sp    = ws;                                   // 64
  float* invd  = sp + 64;                              // 4608
  float* logd  = invd + (size_t)NS * ND;               // 4608
  float* pp    = logd + (size_t)NS * ND;               // 64 (8 used)
  int*   flags = (int*)(pp + 64);                      // 512 ints (288 used)
  float* iD    = (float*)(flags + 512);                // 4*9*16384
  float* Xf    = iD + (size_t)NS * 9 * 16384;          // 4*1152*256
  float* Xb    = Xf + (size_t)NS * ND * NCOUT;         // 4*1152*256
  float* prec  = Xb + (size_t)NS * ND * NCOUT;         // 4*1152*1152
  float* XLY   = prec + (size_t)NS * D2;               // 4*1152*256
  unsigned short* Phi = (unsigned short*)(XLY + (size_t)NS * ND * NCOUT);
  unsigned short* Plo = Phi + (size_t)NS * ND * NK;
  unsigned short* Yhi = Plo + (size_t)NS * ND * NK;
  unsigned short* Ylo = Yhi + (size_t)NCOUT * NK;

  hipMemsetAsync(flags, 0, 512 * sizeof(int), stream);
  k_sqrtp<<<1, 64, 0, stream>>>(lp, sp, pp);
  k_patches<<<dim3(ND, NS), 256, 0, stream>>>(X, sp, Phi, Plo);
  k_ytt<<<NCOUT, 256, 0, stream>>>(u, sp, Yhi, Ylo);
  k_gemm_mfma<<<dim3(11, 9, NS), 256, 0, stream>>>(Phi, Plo, Yhi, Ylo, prec, XLY);

  for (int q = 0; q < 18; ++q) {
    k_chol_panel<<<dim3(NS, 18 - q), 64, 0, stream>>>(prec, invd, logd, q);
    if (q < 17) {
      int m = 17 - q;
      k_chol_update<<<dim3(m, m, NS), 256, 0, stream>>>(prec, q);
    }
  }
  k_invd128<<<dim3(9, NS), 256, 0, stream>>>(prec, iD);

  k_fsolve<<<dim3(9, 4, NS), 256, 0, stream>>>(prec, iD, XLY, Xf, flags);
  k_bsolve<<<dim3(9, 4, NS), 256, 0, stream>>>(prec, iD, Xf, Z, Xb, out, pp, flags);
  k_finalize<<<NS, 256, 0, stream>>>(logd, pp, out + (size_t)NS * NCOUT * ND);
}

// Round 6
// 1880.328 us; speedup vs baseline: 1.4232x; 1.1488x over previous
//
#include <hip/hip_runtime.h>
#include <math.h>

#define NS 4
#define NB 32
#define CIN 128
#define NCOUT 256
#define HWN 256
#define ND 1152
#define NK 8192   // NB*HWN
static const size_t D2 = (size_t)ND * ND;

typedef __attribute__((ext_vector_type(8))) short bf16x8;
typedef __attribute__((ext_vector_type(4))) float f32x4;

static __device__ inline unsigned short f2bf(float x) {
  unsigned int u = __float_as_uint(x);
  unsigned int r = (u + 0x7fffu + ((u >> 16) & 1u)) >> 16;
  return (unsigned short)r;
}
static __device__ inline float bf2f(unsigned short h) {
  return __uint_as_float(((unsigned int)h) << 16);
}

// ---------------- small prep kernels ----------------

__global__ void k_sqrtp(const float* __restrict__ lp, float* __restrict__ sp,
                        float* __restrict__ pp) {
  int b = threadIdx.x;
  if (b < NB) sp[b] = expf(0.5f * lp[b]);
  if (b < 8) pp[b] = 0.f;
}

// 128 threads; each covers p = 2t, 2t+1 (same image row); packed u32 stores.
__global__ __launch_bounds__(128) void k_patches(const float* __restrict__ X,
                                                 const float* __restrict__ sp,
                                                 unsigned short* __restrict__ Phi,
                                                 unsigned short* __restrict__ Plo) {
  int d = blockIdx.x, s = blockIdx.y, t = threadIdx.x;
  int c = d / 9, r = d % 9, ky = r / 3, kx = r % 3;
  int p0 = t * 2;
  int yy = (p0 >> 4) + ky - 1;
  int xx0 = (p0 & 15) + kx - 1;
  bool oky = (yy >= 0 && yy < 16);
  bool ok0 = oky && (xx0 >= 0) && (xx0 < 16);
  bool ok1 = oky && (xx0 + 1 >= 0) && (xx0 + 1 < 16);
  int xo = yy * 16 + xx0;
  size_t base = ((size_t)s * ND + d) * NK + p0;
  for (int b = 0; b < NB; ++b) {
    float sb = sp[b];
    const float* xb = X + ((size_t)(s * NB + b) * CIN + c) * HWN;
    float v0 = ok0 ? xb[xo] * sb : 0.f;
    float v1 = ok1 ? xb[xo + 1] * sb : 0.f;
    unsigned short h0 = f2bf(v0), h1 = f2bf(v1);
    unsigned short l0 = f2bf(v0 - bf2f(h0)), l1 = f2bf(v1 - bf2f(h1));
    size_t idx = base + (size_t)b * HWN;
    *(unsigned int*)(Phi + idx) = (unsigned int)h0 | ((unsigned int)h1 << 16);
    *(unsigned int*)(Plo + idx) = (unsigned int)l0 | ((unsigned int)l1 << 16);
  }
}

__global__ __launch_bounds__(128) void k_ytt(const float* __restrict__ u,
                                             const float* __restrict__ sp,
                                             unsigned short* __restrict__ Yhi,
                                             unsigned short* __restrict__ Ylo) {
  int c = blockIdx.x, t = threadIdx.x;
  int p0 = t * 2;
  for (int b = 0; b < NB; ++b) {
    float sb = sp[b];
    const float* ub = u + ((size_t)b * NCOUT + c) * HWN + p0;
    float v0 = ub[0] * sb, v1 = ub[1] * sb;
    unsigned short h0 = f2bf(v0), h1 = f2bf(v1);
    unsigned short l0 = f2bf(v0 - bf2f(h0)), l1 = f2bf(v1 - bf2f(h1));
    size_t idx = (size_t)c * NK + (size_t)b * HWN + p0;
    *(unsigned int*)(Yhi + idx) = (unsigned int)h0 | ((unsigned int)h1 << 16);
    *(unsigned int*)(Ylo + idx) = (unsigned int)l0 | ((unsigned int)l1 << 16);
  }
}

// ---------------- bf16x3 MFMA XLX/XLY, K-split by 2 (partial sums) ----------------
__global__ __launch_bounds__(256) void k_gemm_mfma(
    const unsigned short* __restrict__ Phi, const unsigned short* __restrict__ Plo,
    const unsigned short* __restrict__ Yhi, const unsigned short* __restrict__ Ylo,
    float* __restrict__ prec, float* __restrict__ prec2,
    float* __restrict__ XLY, float* __restrict__ XLY2) {
  int jt = blockIdx.x, it = blockIdx.y;
  int s = blockIdx.z >> 1, kp = blockIdx.z & 1;
  bool isX = (jt <= it);
  if (!isX && jt < 9) return;
  int i0 = it * 128;
  int j0;
  const unsigned short *Bh, *Bl;
  if (isX) {
    j0 = jt * 128;
    Bh = Phi + ((size_t)s * ND + j0) * NK;
    Bl = Plo + ((size_t)s * ND + j0) * NK;
  } else {
    j0 = (jt - 9) * 128;
    Bh = Yhi + (size_t)j0 * NK;
    Bl = Ylo + (size_t)j0 * NK;
  }
  const unsigned short* Ah = Phi + ((size_t)s * ND + i0) * NK;
  const unsigned short* Al = Plo + ((size_t)s * ND + i0) * NK;

  __shared__ unsigned short sAh[4096], sAl[4096], sBh[4096], sBl[4096];
  int tid = threadIdx.x, wave = tid >> 6, lane = tid & 63;
  int wr = wave >> 1, wc = wave & 1;

  f32x4 zero = {0.f, 0.f, 0.f, 0.f};
  f32x4 acc[4][4];
#pragma unroll
  for (int m = 0; m < 4; ++m)
#pragma unroll
    for (int n = 0; n < 4; ++n) acc[m][n] = zero;

  const unsigned short* srcs[4] = {Ah, Al, Bh, Bl};
  unsigned short* dsts[4] = {sAh, sAl, sBh, sBl};
  int r0l = lane >> 2;
  int ke = (lane & 3) * 8;
  int arow0 = wr * 64 + (lane & 15);
  int brow0 = wc * 64 + (lane & 15);
  int koff = (lane >> 4) * 8;

  int kbeg = kp * (NK / 2), kend = kbeg + NK / 2;
  for (int k0 = kbeg; k0 < kend; k0 += 32) {
    __syncthreads();
#pragma unroll
    for (int f = 0; f < 4; ++f) {
#pragma unroll
      for (int cc = 0; cc < 2; ++cc) {
        int c = wave * 2 + cc;
        const unsigned short* g = srcs[f] + (size_t)(c * 16 + r0l) * NK + k0 + ke;
        unsigned short* l = dsts[f] + c * 512;
        __builtin_amdgcn_global_load_lds(
            (const __attribute__((address_space(1))) void*)g,
            (__attribute__((address_space(3))) void*)l, 16, 0, 0);
      }
    }
    __syncthreads();
    bf16x8 ah[4], al[4], bh[4], bl[4];
#pragma unroll
    for (int m = 0; m < 4; ++m) {
      int off = (arow0 + m * 16) * 32 + koff;
      ah[m] = *(const bf16x8*)&sAh[off];
      al[m] = *(const bf16x8*)&sAl[off];
    }
#pragma unroll
    for (int n = 0; n < 4; ++n) {
      int off = (brow0 + n * 16) * 32 + koff;
      bh[n] = *(const bf16x8*)&sBh[off];
      bl[n] = *(const bf16x8*)&sBl[off];
    }
#pragma unroll
    for (int m = 0; m < 4; ++m)
#pragma unroll
      for (int n = 0; n < 4; ++n) {
        acc[m][n] = __builtin_amdgcn_mfma_f32_16x16x32_bf16(ah[m], bh[n], acc[m][n], 0, 0, 0);
        acc[m][n] = __builtin_amdgcn_mfma_f32_16x16x32_bf16(ah[m], bl[n], acc[m][n], 0, 0, 0);
        acc[m][n] = __builtin_amdgcn_mfma_f32_16x16x32_bf16(al[m], bh[n], acc[m][n], 0, 0, 0);
      }
  }

  if (isX) {
    float* base = (kp ? prec2 : prec) + (size_t)s * D2;
#pragma unroll
    for (int m = 0; m < 4; ++m) {
      int row = i0 + wr * 64 + m * 16 + (lane >> 4) * 4;
#pragma unroll
      for (int n = 0; n < 4; ++n) {
        int col = j0 + wc * 64 + n * 16 + (lane & 15);
        float* cp = base + (size_t)row * ND + col;
#pragma unroll
        for (int r = 0; r < 4; ++r) cp[(size_t)r * ND] = acc[m][n][r];
      }
    }
  } else {
    float* base = (kp ? XLY2 : XLY) + (size_t)s * ND * NCOUT;
#pragma unroll
    for (int m = 0; m < 4; ++m) {
      int row = i0 + wr * 64 + m * 16 + (lane >> 4) * 4;
#pragma unroll
      for (int n = 0; n < 4; ++n) {
        int col = j0 + wc * 64 + n * 16 + (lane & 15);
        float* cp = base + (size_t)row * NCOUT + col;
#pragma unroll
        for (int r = 0; r < 4; ++r) cp[(size_t)r * NCOUT] = acc[m][n][r];
      }
    }
  }
}

// ---------------- persistent DAG Cholesky, 64x64 tiles ----------------
// grid (171, NS): tile (bi,bj), bi>=bj over 18x18. Flags fc[s*324 + i*18 + j].
// Sums the K-split partials + prior*I on load. Diag blocks publish iA64 (inv of diag).
__global__ __launch_bounds__(256, 3) void k_chol_dag(
    float* __restrict__ L, const float* __restrict__ Lp2,
    float* __restrict__ iA64, float* __restrict__ invd, float* __restrict__ logd,
    int* __restrict__ flags) {
  int t0 = blockIdx.x, s = blockIdx.y;
  int bi = 0;
  while ((bi + 1) * (bi + 2) / 2 <= t0) ++bi;
  int bj = t0 - bi * (bi + 1) / 2;
  int ib = bi * 64, jb = bj * 64;
  float* Ls = L + (size_t)s * D2;
  const float* Ps = Lp2 + (size_t)s * D2;
  int* fc = flags + s * 324;

  __shared__ float At[64][68];
  __shared__ float Bt[64][68];
  int tid = threadIdx.x, tx = tid & 15, ty = tid >> 4;
  int lane = tid & 63, w = tid >> 6;

  // load acc = partial0 + partial1 (+ I on diag)
  float acc[4][4];
#pragma unroll
  for (int r = 0; r < 4; ++r) {
    size_t idx = (size_t)(ib + ty * 4 + r) * ND + jb + tx * 4;
    float4 v = *(const float4*)(Ls + idx);
    float4 v2 = *(const float4*)(Ps + idx);
    acc[r][0] = v.x + v2.x; acc[r][1] = v.y + v2.y;
    acc[r][2] = v.z + v2.z; acc[r][3] = v.w + v2.w;
  }
  if (bi == bj) {
#pragma unroll
    for (int r = 0; r < 4; ++r)
#pragma unroll
      for (int e = 0; e < 4; ++e)
        if (ty * 4 + r == tx * 4 + e) acc[r][e] += 1.f;
  }

  // trailing updates: acc -= L(bi,k) @ L(bj,k)^T for k < bj
  for (int k = 0; k < bj; ++k) {
    if (tid == 0) {
      while (__hip_atomic_load(&fc[bi * 18 + k], __ATOMIC_RELAXED,
                               __HIP_MEMORY_SCOPE_AGENT) == 0)
        __builtin_amdgcn_s_sleep(2);
      while (__hip_atomic_load(&fc[bj * 18 + k], __ATOMIC_RELAXED,
                               __HIP_MEMORY_SCOPE_AGENT) == 0)
        __builtin_amdgcn_s_sleep(2);
      (void)__hip_atomic_load(&fc[bj * 18 + k], __ATOMIC_ACQUIRE,
                              __HIP_MEMORY_SCOPE_AGENT);
    }
    __syncthreads();
    int kb = k * 64;
    {
      int a2 = tid >> 2, km = (tid & 3) * 4;
#pragma unroll
      for (int m = 0; m < 4; ++m) {
        float4 v = *(const float4*)(Ls + (size_t)(ib + a2) * ND + kb + km + m * 16);
        At[km + m * 16 + 0][a2] = v.x;
        At[km + m * 16 + 1][a2] = v.y;
        At[km + m * 16 + 2][a2] = v.z;
        At[km + m * 16 + 3][a2] = v.w;
        float4 u4 = *(const float4*)(Ls + (size_t)(jb + a2) * ND + kb + km + m * 16);
        Bt[km + m * 16 + 0][a2] = u4.x;
        Bt[km + m * 16 + 1][a2] = u4.y;
        Bt[km + m * 16 + 2][a2] = u4.z;
        Bt[km + m * 16 + 3][a2] = u4.w;
      }
    }
    __syncthreads();
#pragma unroll
    for (int kc = 0; kc < 64; ++kc) {
      float4 a4 = *(const float4*)&At[kc][ty * 4];
      float4 b4 = *(const float4*)&Bt[kc][tx * 4];
      float ar[4] = {a4.x, a4.y, a4.z, a4.w};
      float br[4] = {b4.x, b4.y, b4.z, b4.w};
#pragma unroll
      for (int r = 0; r < 4; ++r)
#pragma unroll
        for (int e = 0; e < 4; ++e) acc[r][e] = fmaf(-ar[r], br[e], acc[r][e]);
    }
    __syncthreads();
  }

  if (bi == bj) {
    // ---- diag: factor + invert ----
#pragma unroll
    for (int r = 0; r < 4; ++r)
#pragma unroll
      for (int e = 0; e < 4; ++e) At[ty * 4 + r][tx * 4 + e] = acc[r][e];
    __syncthreads();
    if (w == 0) {
      float a[64];
#pragma unroll
      for (int tt = 0; tt < 64; ++tt) a[tt] = At[lane][tt];
      float diagv = 1.f;
#pragma unroll
      for (int j = 0; j < 64; ++j) {
        float dj = __shfl(a[j], j, 64);
        float rinv = 1.0f / sqrtf(dj);
        a[j] *= rinv;
        if (lane == j) diagv = a[j];
#pragma unroll
        for (int tt = j + 1; tt < 64; ++tt) {
          float ltj = __shfl(a[j], tt, 64);
          a[tt] = fmaf(-a[j], ltj, a[tt]);
        }
      }
#pragma unroll
      for (int tt = 0; tt < 64; ++tt) At[lane][tt] = (tt <= lane) ? a[tt] : 0.f;
      invd[s * ND + ib + lane] = 1.0f / diagv;
      logd[s * ND + ib + lane] = logf(diagv);
    }
    __syncthreads();
    // copy factored L tile to global (all threads); wave1 inverts concurrently
    {
      int rr = tid >> 2, c4 = (tid & 3) * 16;
#pragma unroll
      for (int m = 0; m < 4; ++m)
        *(float4*)(Ls + (size_t)(ib + rr) * ND + ib + c4 + m * 4) =
            *(const float4*)&At[rr][c4 + m * 4];
    }
    if (w == 1) {
      float x[64];
#pragma unroll
      for (int i = 0; i < 64; ++i) x[i] = (i == lane) ? 1.f : 0.f;
      for (int j = 0; j < 64; ++j) {
        float xj = x[j] / At[j][j];
        x[j] = xj;
        for (int i = j + 1; i < 64; ++i) x[i] = fmaf(-At[i][j], xj, x[i]);
      }
#pragma unroll
      for (int i = 0; i < 64; ++i) Bt[i][lane] = x[i];
    }
    __syncthreads();
    {
      float* q = iA64 + (size_t)(s * 18 + bi) * 4096;
      int rr = tid >> 2, c4 = (tid & 3) * 16;
#pragma unroll
      for (int m = 0; m < 4; ++m)
        *(float4*)(q + rr * 64 + c4 + m * 4) = *(const float4*)&Bt[rr][c4 + m * 4];
    }
    __threadfence();
    __syncthreads();
    if (tid == 0)
      __hip_atomic_store(&fc[bi * 18 + bi], 1, __ATOMIC_RELEASE,
                         __HIP_MEMORY_SCOPE_AGENT);
  } else {
    // ---- off-diag: L(bi,bj) = acc @ iA(bj)^T ----
#pragma unroll
    for (int r = 0; r < 4; ++r)
#pragma unroll
      for (int e = 0; e < 4; ++e) At[tx * 4 + e][ty * 4 + r] = acc[r][e];
    __syncthreads();
    if (tid == 0) {
      while (__hip_atomic_load(&fc[bj * 18 + bj], __ATOMIC_RELAXED,
                               __HIP_MEMORY_SCOPE_AGENT) == 0)
        __builtin_amdgcn_s_sleep(2);
      (void)__hip_atomic_load(&fc[bj * 18 + bj], __ATOMIC_ACQUIRE,
                              __HIP_MEMORY_SCOPE_AGENT);
    }
    __syncthreads();
    {
      const float* q = iA64 + (size_t)(s * 18 + bj) * 4096;
      int a2 = tid >> 2, km = (tid & 3) * 4;
#pragma unroll
      for (int m = 0; m < 4; ++m) {
        float4 v = *(const float4*)(q + a2 * 64 + km + m * 16);
        Bt[km + m * 16 + 0][a2] = v.x;
        Bt[km + m * 16 + 1][a2] = v.y;
        Bt[km + m * 16 + 2][a2] = v.z;
        Bt[km + m * 16 + 3][a2] = v.w;
      }
    }
    __syncthreads();
    float acc2[4][4] = {};
#pragma unroll
    for (int kc = 0; kc < 64; ++kc) {
      float4 a4 = *(const float4*)&At[kc][ty * 4];
      float4 b4 = *(const float4*)&Bt[kc][tx * 4];
      float ar[4] = {a4.x, a4.y, a4.z, a4.w};
      float br[4] = {b4.x, b4.y, b4.z, b4.w};
#pragma unroll
      for (int r = 0; r < 4; ++r)
#pragma unroll
        for (int e = 0; e < 4; ++e) acc2[r][e] = fmaf(ar[r], br[e], acc2[r][e]);
    }
#pragma unroll
    for (int r = 0; r < 4; ++r) {
      float4 v = {acc2[r][0], acc2[r][1], acc2[r][2], acc2[r][3]};
      *(float4*)(Ls + (size_t)(ib + ty * 4 + r) * ND + jb + tx * 4) = v;
    }
    __threadfence();
    __syncthreads();
    if (tid == 0)
      __hip_atomic_store(&fc[bi * 18 + bj], 1, __ATOMIC_RELEASE,
                         __HIP_MEMORY_SCOPE_AGENT);
  }
}

// ---------------- invert 128x128 diag blocks (wave-parallel, unchanged) ----------------
__global__ __launch_bounds__(256) void k_invd128(const float* __restrict__ L,
                                                 float* __restrict__ iD) {
  int q = blockIdx.x, s = blockIdx.y;
  int tid = threadIdx.x, lane = tid & 63, w = tid >> 6;
  const float* Ls = L + (size_t)s * D2;
  float* out = iD + ((size_t)(s * 9 + q)) * 16384;
  int b0 = q * 128;
  __shared__ float inv0[64][65];
  __shared__ float invCt[64][65];
  __shared__ float Bt[64][65];
  __shared__ float Tl[64][65];

  if (w < 2) {
    const float* base = Ls + (size_t)(b0 + w * 64) * ND + b0 + w * 64;
    float lcol[64], x[64];
#pragma unroll
    for (int i = 0; i < 64; ++i) {
      lcol[i] = base[(size_t)i * ND + lane];
      x[i] = (i == lane) ? 1.f : 0.f;
    }
#pragma unroll
    for (int j = 0; j < 64; ++j) {
      float ljj = __shfl(lcol[j], j, 64);
      float xj = x[j] / ljj;
      x[j] = xj;
#pragma unroll
      for (int i = j + 1; i < 64; ++i) {
        float lij = __shfl(lcol[i], j, 64);
        x[i] = fmaf(-lij, xj, x[i]);
      }
    }
    if (w == 0) {
#pragma unroll
      for (int i = 0; i < 64; ++i) inv0[i][lane] = x[i];
    } else {
#pragma unroll
      for (int i = 0; i < 64; ++i) invCt[lane][i] = x[i];
    }
  } else {
    int t = tid - 128;
    int i = t & 63, kh = (t >> 6) * 32;
    const float* src = Ls + (size_t)(b0 + 64 + i) * ND + b0 + kh;
#pragma unroll
    for (int m = 0; m < 8; ++m) {
      float4 v = *(const float4*)(src + m * 4);
      Bt[kh + m * 4 + 0][i] = v.x;
      Bt[kh + m * 4 + 1][i] = v.y;
      Bt[kh + m * 4 + 2][i] = v.z;
      Bt[kh + m * 4 + 3][i] = v.w;
    }
  }
  __syncthreads();

  int tx = tid & 15, ty = tid >> 4;
  float acc[4][4] = {};
#pragma unroll
  for (int k = 0; k < 64; ++k) {
    float a4[4], b4[4];
#pragma unroll
    for (int e = 0; e < 4; ++e) { a4[e] = Bt[k][ty * 4 + e]; b4[e] = inv0[k][tx * 4 + e]; }
#pragma unroll
    for (int r = 0; r < 4; ++r)
#pragma unroll
      for (int e = 0; e < 4; ++e) acc[r][e] = fmaf(a4[r], b4[e], acc[r][e]);
  }
#pragma unroll
  for (int r = 0; r < 4; ++r)
#pragma unroll
    for (int e = 0; e < 4; ++e) Tl[ty * 4 + r][tx * 4 + e] = acc[r][e];
  __syncthreads();
  float acc2[4][4] = {};
#pragma unroll
  for (int k = 0; k < 64; ++k) {
    float a4[4], b4[4];
#pragma unroll
    for (int e = 0; e < 4; ++e) { a4[e] = invCt[k][ty * 4 + e]; b4[e] = Tl[k][tx * 4 + e]; }
#pragma unroll
    for (int r = 0; r < 4; ++r)
#pragma unroll
      for (int e = 0; e < 4; ++e) acc2[r][e] = fmaf(a4[r], b4[e], acc2[r][e]);
  }
  {
    int rrow = tid >> 2, cc = (tid & 3) * 32;
    float* o = out + rrow * 128 + cc;
    if (cc < 64) {
#pragma unroll
      for (int m = 0; m < 8; ++m) {
        float4 v = {inv0[rrow][cc + m * 4 + 0], inv0[rrow][cc + m * 4 + 1],
                    inv0[rrow][cc + m * 4 + 2], inv0[rrow][cc + m * 4 + 3]};
        *(float4*)(o + m * 4) = v;
      }
    } else {
      float4 z = {0.f, 0.f, 0.f, 0.f};
#pragma unroll
      for (int m = 0; m < 8; ++m) *(float4*)(o + m * 4) = z;
    }
  }
#pragma unroll
  for (int r = 0; r < 4; ++r) {
    float4 v = {-acc2[r][0], -acc2[r][1], -acc2[r][2], -acc2[r][3]};
    *(float4*)(out + (size_t)(64 + ty * 4 + r) * 128 + tx * 4) = v;
  }
  {
    int i = tid >> 2, jc = (tid & 3) * 16;
#pragma unroll
    for (int m = 0; m < 4; ++m) {
      float4 v = {invCt[jc + m * 4 + 0][i], invCt[jc + m * 4 + 1][i],
                  invCt[jc + m * 4 + 2][i], invCt[jc + m * 4 + 3][i]};
      *(float4*)(out + (size_t)(64 + i) * 128 + 64 + jc + m * 4) = v;
    }
  }
}

// ---------------- merged persistent fwd+bwd solve (fused addz/writewm) ----------------
__global__ __launch_bounds__(256) void k_solve2(
    const float* __restrict__ L, const float* __restrict__ iD,
    const float* __restrict__ B1, const float* __restrict__ B2,
    const float* __restrict__ Z, float* __restrict__ Xf, float* __restrict__ Xb,
    float* __restrict__ Wm, float* __restrict__ pp, int* __restrict__ flags) {
  int r = blockIdx.x, ct = blockIdx.y, s = blockIdx.z;
  int rb = r * 128, cb = ct * 64;
  const float* Ls = L + (size_t)s * D2;
  const float* Dq = iD + ((size_t)(s * 9 + r)) * 16384;
  float* Xfs = Xf + (size_t)s * ND * NCOUT;
  float* Xbs = Xb + (size_t)s * ND * NCOUT;
  int fbf = 1296 + (s * 4 + ct) * 9;
  int fbb = 1440 + (s * 4 + ct) * 9;

  __shared__ float sA[32][132];
  __shared__ float sB[32][68];
  __shared__ float red[8];
  int tid = threadIdx.x, tx = tid & 15, ty = tid >> 4;
  int wave = tid >> 6, lane = tid & 63;

  // ======== forward ========
  float acc[8][4];
#pragma unroll
  for (int ii = 0; ii < 8; ++ii) {
    size_t idx = (size_t)s * ND * NCOUT + (size_t)(rb + ty * 8 + ii) * NCOUT + cb + tx * 4;
    float4 v = *(const float4*)(B1 + idx);
    float4 v2 = *(const float4*)(B2 + idx);
    acc[ii][0] = v.x + v2.x; acc[ii][1] = v.y + v2.y;
    acc[ii][2] = v.z + v2.z; acc[ii][3] = v.w + v2.w;
  }
  for (int q = 0; q < r; ++q) {
    if (tid == 0) {
      while (__hip_atomic_load(&flags[fbf + q], __ATOMIC_RELAXED,
                               __HIP_MEMORY_SCOPE_AGENT) == 0)
        __builtin_amdgcn_s_sleep(2);
      (void)__hip_atomic_load(&flags[fbf + q], __ATOMIC_ACQUIRE,
                              __HIP_MEMORY_SCOPE_AGENT);
    }
    __syncthreads();
    int qb = q * 128;
    for (int kk = 0; kk < 4; ++kk) {
      __syncthreads();
      {
        int i = tid >> 1, kb = (tid & 1) * 16;
        const float* src = Ls + (size_t)(rb + i) * ND + qb + kk * 32 + kb;
#pragma unroll
        for (int m = 0; m < 4; ++m) {
          float4 v = *(const float4*)(src + m * 4);
          sA[kb + m * 4 + 0][i] = v.x;
          sA[kb + m * 4 + 1][i] = v.y;
          sA[kb + m * 4 + 2][i] = v.z;
          sA[kb + m * 4 + 3][i] = v.w;
        }
      }
      {
        int k = tid >> 3, jb2 = (tid & 7) * 8;
        const float* src = Xfs + (size_t)(qb + kk * 32 + k) * NCOUT + cb + jb2;
        float4 v0 = *(const float4*)src;
        float4 v1 = *(const float4*)(src + 4);
        *(float4*)&sB[k][jb2] = v0;
        *(float4*)&sB[k][jb2 + 4] = v1;
      }
      __syncthreads();
#pragma unroll
      for (int k = 0; k < 32; ++k) {
        float4 a0 = *(const float4*)&sA[k][ty * 8];
        float4 a1 = *(const float4*)&sA[k][ty * 8 + 4];
        float4 b0 = *(const float4*)&sB[k][tx * 4];
        float a[8] = {a0.x, a0.y, a0.z, a0.w, a1.x, a1.y, a1.z, a1.w};
        float b[4] = {b0.x, b0.y, b0.z, b0.w};
#pragma unroll
        for (int ii = 0; ii < 8; ++ii)
#pragma unroll
          for (int j = 0; j < 4; ++j) acc[ii][j] = fmaf(-a[ii], b[j], acc[ii][j]);
      }
    }
  }
  float acc2[8][4] = {};
  for (int kk = 0; kk < 4; ++kk) {
    __syncthreads();
    if ((ty >> 2) == kk) {
      int kloc = ty * 8 - kk * 32;
#pragma unroll
      for (int ii = 0; ii < 8; ++ii) {
        float4 v = {acc[ii][0], acc[ii][1], acc[ii][2], acc[ii][3]};
        *(float4*)&sB[kloc + ii][tx * 4] = v;
      }
    }
    {
      int i = tid >> 1, kb = (tid & 1) * 16;
      const float* src = Dq + (size_t)i * 128 + kk * 32 + kb;
#pragma unroll
      for (int m = 0; m < 4; ++m) {
        float4 v = *(const float4*)(src + m * 4);
        sA[kb + m * 4 + 0][i] = v.x;
        sA[kb + m * 4 + 1][i] = v.y;
        sA[kb + m * 4 + 2][i] = v.z;
        sA[kb + m * 4 + 3][i] = v.w;
      }
    }
    __syncthreads();
#pragma unroll
    for (int k = 0; k < 32; ++k) {
      float4 a0 = *(const float4*)&sA[k][ty * 8];
      float4 a1 = *(const float4*)&sA[k][ty * 8 + 4];
      float4 b0 = *(const float4*)&sB[k][tx * 4];
      float a[8] = {a0.x, a0.y, a0.z, a0.w, a1.x, a1.y, a1.z, a1.w};
      float b[4] = {b0.x, b0.y, b0.z, b0.w};
#pragma unroll
      for (int ii = 0; ii < 8; ++ii)
#pragma unroll
        for (int j = 0; j < 4; ++j) acc2[ii][j] = fmaf(a[ii], b[j], acc2[ii][j]);
    }
  }
#pragma unroll
  for (int ii = 0; ii < 8; ++ii) {
    float4 v = {acc2[ii][0], acc2[ii][1], acc2[ii][2], acc2[ii][3]};
    *(float4*)(Xfs + (size_t)(rb + ty * 8 + ii) * NCOUT + cb + tx * 4) = v;
  }
  __threadfence();
  __syncthreads();
  if (tid == 0)
    __hip_atomic_store(&flags[fbf + r], 1, __ATOMIC_RELEASE,
                       __HIP_MEMORY_SCOPE_AGENT);

  // ======== backward (init from fwd result in registers) ========
#pragma unroll
  for (int ii = 0; ii < 8; ++ii)
#pragma unroll
    for (int j = 0; j < 4; ++j) acc[ii][j] = acc2[ii][j];

  float zp = 0.f;
  for (int kk = 0; kk < 4; ++kk) {
    __syncthreads();
    {
      int c = tid >> 2, d8 = (tid & 3) * 8;
      const float* src = Z + ((size_t)(s * NCOUT) + cb + c) * ND + rb + kk * 32 + d8;
      float4 v0 = *(const float4*)src;
      float4 v1 = *(const float4*)(src + 4);
      sA[d8 + 0][c] = v0.x; sA[d8 + 1][c] = v0.y; sA[d8 + 2][c] = v0.z; sA[d8 + 3][c] = v0.w;
      sA[d8 + 4][c] = v1.x; sA[d8 + 5][c] = v1.y; sA[d8 + 6][c] = v1.z; sA[d8 + 7][c] = v1.w;
      zp += v0.x * v0.x + v0.y * v0.y + v0.z * v0.z + v0.w * v0.w;
      zp += v1.x * v1.x + v1.y * v1.y + v1.z * v1.z + v1.w * v1.w;
    }
    __syncthreads();
    if ((ty >> 2) == kk) {
      int kloc = ty * 8 - kk * 32;
#pragma unroll
      for (int ii = 0; ii < 8; ++ii) {
        float4 v = *(const float4*)&sA[kloc + ii][tx * 4];
        acc[ii][0] += v.x; acc[ii][1] += v.y; acc[ii][2] += v.z; acc[ii][3] += v.w;
      }
    }
  }
#pragma unroll
  for (int m2 = 32; m2 >= 1; m2 >>= 1) zp += __shfl_xor(zp, m2, 64);
  if (lane == 0) red[wave] = zp;
  __syncthreads();
  if (tid == 0) atomicAdd(pp + s, red[0] + red[1] + red[2] + red[3]);

  for (int q = 8; q > r; --q) {
    if (tid == 0) {
      while (__hip_atomic_load(&flags[fbb + q], __ATOMIC_RELAXED,
                               __HIP_MEMORY_SCOPE_AGENT) == 0)
        __builtin_amdgcn_s_sleep(2);
      (void)__hip_atomic_load(&flags[fbb + q], __ATOMIC_ACQUIRE,
                              __HIP_MEMORY_SCOPE_AGENT);
    }
    __syncthreads();
    int qb = q * 128;
    for (int kk = 0; kk < 4; ++kk) {
      __syncthreads();
      {
        int k = tid >> 3, ib2 = (tid & 7) * 16;
        const float* src = Ls + (size_t)(qb + kk * 32 + k) * ND + rb + ib2;
#pragma unroll
        for (int m = 0; m < 4; ++m)
          *(float4*)&sA[k][ib2 + m * 4] = *(const float4*)(src + m * 4);
      }
      {
        int k = tid >> 3, jb2 = (tid & 7) * 8;
        const float* src = Xbs + (size_t)(qb + kk * 32 + k) * NCOUT + cb + jb2;
        float4 v0 = *(const float4*)src;
        float4 v1 = *(const float4*)(src + 4);
        *(float4*)&sB[k][jb2] = v0;
        *(float4*)&sB[k][jb2 + 4] = v1;
      }
      __syncthreads();
#pragma unroll
      for (int k = 0; k < 32; ++k) {
        float4 a0 = *(const float4*)&sA[k][ty * 8];
        float4 a1 = *(const float4*)&sA[k][ty * 8 + 4];
        float4 b0 = *(const float4*)&sB[k][tx * 4];
        float a[8] = {a0.x, a0.y, a0.z, a0.w, a1.x, a1.y, a1.z, a1.w};
        float b[4] = {b0.x, b0.y, b0.z, b0.w};
#pragma unroll
        for (int ii = 0; ii < 8; ++ii)
#pragma unroll
          for (int j = 0; j < 4; ++j) acc[ii][j] = fmaf(-a[ii], b[j], acc[ii][j]);
      }
    }
  }
#pragma unroll
  for (int ii = 0; ii < 8; ++ii)
#pragma unroll
    for (int j = 0; j < 4; ++j) acc2[ii][j] = 0.f;
  for (int kk = 0; kk < 4; ++kk) {
    __syncthreads();
    if ((ty >> 2) == kk) {
      int kloc = ty * 8 - kk * 32;
#pragma unroll
      for (int ii = 0; ii < 8; ++ii) {
        float4 v = {acc[ii][0], acc[ii][1], acc[ii][2], acc[ii][3]};
        *(float4*)&sB[kloc + ii][tx * 4] = v;
      }
    }
    {
      int k = tid >> 3, ib2 = (tid & 7) * 16;
      const float* src = Dq + (size_t)(kk * 32 + k) * 128 + ib2;
#pragma unroll
      for (int m = 0; m < 4; ++m)
        *(float4*)&sA[k][ib2 + m * 4] = *(const float4*)(src + m * 4);
    }
    __syncthreads();
#pragma unroll
    for (int k = 0; k < 32; ++k) {
      float4 a0 = *(const float4*)&sA[k][ty * 8];
      float4 a1 = *(const float4*)&sA[k][ty * 8 + 4];
      float4 b0 = *(const float4*)&sB[k][tx * 4];
      float a[8] = {a0.x, a0.y, a0.z, a0.w, a1.x, a1.y, a1.z, a1.w};
      float b[4] = {b0.x, b0.y, b0.z, b0.w};
#pragma unroll
      for (int ii = 0; ii < 8; ++ii)
#pragma unroll
        for (int j = 0; j < 4; ++j) acc2[ii][j] = fmaf(a[ii], b[j], acc2[ii][j]);
    }
  }
#pragma unroll
  for (int ii = 0; ii < 8; ++ii) {
    float4 v = {acc2[ii][0], acc2[ii][1], acc2[ii][2], acc2[ii][3]};
    *(float4*)(Xbs + (size_t)(rb + ty * 8 + ii) * NCOUT + cb + tx * 4) = v;
  }
  __threadfence();
  __syncthreads();
  if (tid == 0)
    __hip_atomic_store(&flags[fbb + r], 1, __ATOMIC_RELEASE,
                       __HIP_MEMORY_SCOPE_AGENT);
  float wp = 0.f;
#pragma unroll
  for (int ii = 0; ii < 8; ++ii)
#pragma unroll
    for (int j = 0; j < 4; ++j) wp += acc2[ii][j] * acc2[ii][j];
#pragma unroll
  for (int m2 = 32; m2 >= 1; m2 >>= 1) wp += __shfl_xor(wp, m2, 64);
  __syncthreads();
  if (lane == 0) red[wave] = wp;
  __syncthreads();
  if (tid == 0) atomicAdd(pp + 4 + s, red[0] + red[1] + red[2] + red[3]);
  for (int kk = 0; kk < 4; ++kk) {
    __syncthreads();
    if ((ty >> 2) == kk) {
      int kloc = ty * 8 - kk * 32;
#pragma unroll
      for (int ii = 0; ii < 8; ++ii) {
        float4 v = {acc2[ii][0], acc2[ii][1], acc2[ii][2], acc2[ii][3]};
        *(float4*)&sB[kloc + ii][tx * 4] = v;
      }
    }
    __syncthreads();
    {
      int c = tid >> 2, d8 = (tid & 3) * 8;
      float t0 = sB[d8 + 0][c], t1 = sB[d8 + 1][c], t2 = sB[d8 + 2][c], t3 = sB[d8 + 3][c];
      float t4 = sB[d8 + 4][c], t5 = sB[d8 + 5][c], t6 = sB[d8 + 6][c], t7 = sB[d8 + 7][c];
      float* dst = Wm + ((size_t)(s * NCOUT) + cb + c) * ND + rb + kk * 32 + d8;
      float4 w0 = {t0, t1, t2, t3}, w1 = {t4, t5, t6, t7};
      *(float4*)dst = w0;
      *(float4*)(dst + 4) = w1;
    }
  }
}

__global__ __launch_bounds__(256) void k_finalize(const float* __restrict__ logd,
                                                  const float* __restrict__ pp,
                                                  float* __restrict__ out) {
  int s = blockIdx.x, tid = threadIdx.x;
  __shared__ float r0[256];
  float l = 0.f;
  for (int i = tid; i < ND; i += 256) l += logd[s * ND + i];
  r0[tid] = l;
  __syncthreads();
  for (int off = 128; off; off >>= 1) {
    if (tid < off) r0[tid] += r0[tid + off];
    __syncthreads();
  }
  if (tid == 0) {
    float logdet = 2.0f * r0[0];
    out[s] = 0.5f * (pp[s] - pp[4 + s]) - 128.0f * logdet;
  }
}

// ---------------- launcher ----------------
extern "C" void kernel_launch(void* const* d_in, const int* in_sizes, int n_in,
                              void* d_out, int out_size, void* d_ws, size_t ws_size,
                              hipStream_t stream) {
  const float* X = (const float*)d_in[0];
  const float* u = (const float*)d_in[1];
  const float* lp = (const float*)d_in[2];
  const float* Z = (const float*)d_in[3];
  float* out = (float*)d_out;

  float* ws = (float*)d_ws;
  float* sp    = ws;                                    // 64
  float* invd  = sp + 64;                               // 4608
  float* logd  = invd + (size_t)NS * ND;                // 4608
  float* pp    = logd + (size_t)NS * ND;                // 64
  int*   flags = (int*)(pp + 64);                       // 2048 ints (1584 used)
  float* iD    = (float*)(flags + 2048);                // 4*9*16384
  float* iA64  = iD + (size_t)NS * 9 * 16384;           // 4*18*4096
  float* Xf    = iA64 + (size_t)NS * 18 * 4096;         // 4*1152*256
  float* Xb    = Xf + (size_t)NS * ND * NCOUT;          // 4*1152*256
  float* prec  = Xb + (size_t)NS * ND * NCOUT;          // 4*1152*1152
  float* prec2 = prec + (size_t)NS * D2;                // 4*1152*1152
  float* XLY   = prec2 + (size_t)NS * D2;               // 4*1152*256
  float* XLY2  = XLY + (size_t)NS * ND * NCOUT;         // 4*1152*256
  unsigned short* Phi = (unsigned short*)(XLY2 + (size_t)NS * ND * NCOUT);
  unsigned short* Plo = Phi + (size_t)NS * ND * NK;
  unsigned short* Yhi = Plo + (size_t)NS * ND * NK;
  unsigned short* Ylo = Yhi + (size_t)NCOUT * NK;

  hipMemsetAsync(flags, 0, 2048 * sizeof(int), stream);
  k_sqrtp<<<1, 64, 0, stream>>>(lp, sp, pp);
  k_patches<<<dim3(ND, NS), 128, 0, stream>>>(X, sp, Phi, Plo);
  k_ytt<<<NCOUT, 128, 0, stream>>>(u, sp, Yhi, Ylo);
  k_gemm_mfma<<<dim3(11, 9, NS * 2), 256, 0, stream>>>(Phi, Plo, Yhi, Ylo, prec,
                                                       prec2, XLY, XLY2);
  k_chol_dag<<<dim3(171, NS), 256, 0, stream>>>(prec, prec2, iA64, invd, logd, flags);
  k_invd128<<<dim3(9, NS), 256, 0, stream>>>(prec, iD);
  k_solve2<<<dim3(9, 4, NS), 256, 0, stream>>>(prec, iD, XLY, XLY2, Z, Xf, Xb,
                                               out, pp, flags);
  k_finalize<<<NS, 256, 0, stream>>>(logd, pp, out + (size_t)NS * NCOUT * ND);
}